// Round 3
// baseline (1264.918 us; speedup 1.0000x reference)
//
#include <hip/hip_runtime.h>

typedef unsigned int   u32;
typedef unsigned long long u64;

// ---------------- helpers ----------------
__device__ __forceinline__ float fast_tanh(float x) {
    x = fminf(fmaxf(x, -15.f), 15.f);
    float e = __expf(2.f * x);
    return __fdividef(e - 1.f, e + 1.f);
}

// ---------------- workspace layout (bytes, all fp32) ----------------
// OF_XG: xg0 (layer-0 gates), later reused for PQ.  OF_PQ: xg1 (layer-1 gates).
// hist: 2x256x400 u64 tag-versioned (reused by both layers, disjoint tag ranges).
#define OF_XG   ((size_t)0)
#define OF_H    (OF_XG + 3276800)
#define OF_PQ   (OF_H  + 1638400)
#define OF_U    (OF_PQ + 3276800)

// ---- tag-verified hist read: spin until all 4 entries carry the expected tag ----
// layer tag ranges: layer0 base=0 -> tags 1..256; layer1 base=256 -> tags 257..512.
__device__ __forceinline__ float4 hist4_spin(const u64* __restrict__ hist, int t, int k, u32 base) {
    const u64* p; u32 want;
    if (k < 400) { p = hist + (size_t)t * 400 + k;                        want = base + (u32)t + 1u; }
    else         { p = hist + 102400 + (size_t)(255 - t) * 400 + (k - 400); want = base + (u32)(255 - t) + 1u; }
    for (;;) {
        u64 a = __hip_atomic_load(p + 0, __ATOMIC_RELAXED, __HIP_MEMORY_SCOPE_AGENT);
        u64 b = __hip_atomic_load(p + 1, __ATOMIC_RELAXED, __HIP_MEMORY_SCOPE_AGENT);
        u64 c = __hip_atomic_load(p + 2, __ATOMIC_RELAXED, __HIP_MEMORY_SCOPE_AGENT);
        u64 d = __hip_atomic_load(p + 3, __ATOMIC_RELAXED, __HIP_MEMORY_SCOPE_AGENT);
        if ((u32)(a >> 32) == want && (u32)(b >> 32) == want &&
            (u32)(c >> 32) == want && (u32)(d >> 32) == want)
            return make_float4(__uint_as_float((u32)a), __uint_as_float((u32)b),
                               __uint_as_float((u32)c), __uint_as_float((u32)d));
        __builtin_amdgcn_s_sleep(32);   // gentle: ~2k cycles between retries while waiting
    }
}

// ---- shared GEMM micro-kernel pieces (64x64 tile, 16-deep K step) ----
__device__ __forceinline__ void stage16(float (*As)[68], float (*Bs)[68],
                                        int lk, int lr, float4 av, float4 bv) {
    __syncthreads();
    As[lk + 0][lr] = av.x; As[lk + 1][lr] = av.y; As[lk + 2][lr] = av.z; As[lk + 3][lr] = av.w;
    Bs[lk + 0][lr] = bv.x; Bs[lk + 1][lr] = bv.y; Bs[lk + 2][lr] = bv.z; Bs[lk + 3][lr] = bv.w;
    __syncthreads();
}

__device__ __forceinline__ void fma16(float acc[4][4], const float (*As)[68], const float (*Bs)[68],
                                      int tx, int ty) {
    #pragma unroll
    for (int kk = 0; kk < 16; ++kk) {
        float4 a4 = *(const float4*)&As[kk][ty * 4];
        float4 b4 = *(const float4*)&Bs[kk][tx * 4];
        acc[0][0] += a4.x * b4.x; acc[0][1] += a4.x * b4.y; acc[0][2] += a4.x * b4.z; acc[0][3] += a4.x * b4.w;
        acc[1][0] += a4.y * b4.x; acc[1][1] += a4.y * b4.y; acc[1][2] += a4.y * b4.z; acc[1][3] += a4.y * b4.w;
        acc[2][0] += a4.z * b4.x; acc[2][1] += a4.z * b4.y; acc[2][2] += a4.z * b4.z; acc[2][3] += a4.z * b4.w;
        acc[3][0] += a4.w * b4.x; acc[3][1] += a4.w * b4.y; acc[3][2] += a4.w * b4.z; acc[3][3] += a4.w * b4.w;
    }
}

// ---------------- GEMM with A gathered from embeddings (layer-0 xg) ----------------
__global__ __launch_bounds__(256)
void gemm_embed_kernel(const int* __restrict__ words, const int* __restrict__ tags,
                       const float* __restrict__ wemb, const float* __restrict__ temb,
                       const float* __restrict__ B,
                       const float* __restrict__ bias1, const float* __restrict__ bias2,
                       float* __restrict__ C) {
    int t0 = blockIdx.x * 64;
    int n0 = blockIdx.y * 64;
    int tid = threadIdx.x;
    int tx = tid & 15, ty = tid >> 4;
    int lr = tid >> 2, lk = (tid & 3) * 4;
    __shared__ float As[16][68];
    __shared__ float Bs[16][68];
    float acc[4][4] = {};

    int t = t0 + lr;
    const float* arow0 = wemb + (size_t)words[t] * 300;
    const float* arow1 = temb + (size_t)tags[t] * 100 - 300;   // indexed by k directly

    for (int k0 = 0; k0 < 400; k0 += 16) {
        int k = k0 + lk;   // 300 % 4 == 0, so each float4 stays in one table
        float4 av = (k < 300) ? *(const float4*)(arow0 + k) : *(const float4*)(arow1 + k);
        float4 bv = *(const float4*)(B + (size_t)(n0 + lr) * 400 + k);
        stage16(As, Bs, lk, lr, av, bv);
        fma16(acc, As, Bs, tx, ty);
    }
    float bs[4];
    #pragma unroll
    for (int j = 0; j < 4; ++j) {
        int n = n0 + tx * 4 + j;
        bs[j] = bias1[n] + bias2[n];
    }
    #pragma unroll
    for (int i = 0; i < 4; ++i) {
        int tr = t0 + ty * 4 + i;
        float4 o;
        o.x = acc[i][0] + bs[0]; o.y = acc[i][1] + bs[1];
        o.z = acc[i][2] + bs[2]; o.w = acc[i][3] + bs[3];
        *(float4*)(C + (size_t)tr * 3200 + n0 + tx * 4) = o;
    }
}

// ---------------- persistent distributed LSTM body (exact R4 logic) ----------------
#define LSTM_G 50
__device__ __forceinline__ void lstm_body(int bid,
                 const float* __restrict__ Whh,   // (2,1600,400)
                 const float* __restrict__ h0,    // (4,400)
                 const float* __restrict__ c0,    // (4,400)
                 int hc_base,
                 const float* __restrict__ xg,    // (256,3200): [t][d*1600 + gaterow]
                 u64* __restrict__ hist,          // (2,256,400)
                 u32 tag_base,
                 float (*hbuf)[416]) {
    const int T = 256;
    int d  = bid / LSTM_G;
    int wg = bid % LSTM_G;
    int a8 = wg * 8;
    int tid = threadIdx.x;
    int w = tid >> 6, lane = tid & 63;
    int c = lane & 7, r = lane >> 3;
    int gate = r >> 1, jj = r & 1;
    int gr = gate * 400 + a8 + 2 * w + jj;

    float4 wv[13];
    const float* wrow = Whh + (size_t)d * 640000 + (size_t)gr * 400;
    #pragma unroll
    for (int i = 0; i < 13; ++i) {
        int k = 4 * (c + 8 * i);
        wv[i] = (k + 3 < 400) ? *(const float4*)(wrow + k) : make_float4(0.f, 0.f, 0.f, 0.f);
    }
    if (tid < 16) { hbuf[0][400 + tid] = 0.f; hbuf[1][400 + tid] = 0.f; }

    float c_state = 0.f;
    if (lane == 0 || lane == 8)
        c_state = c0[(hc_base + d) * 400 + a8 + 2 * w + jj];

    u64* hst = hist + (size_t)d * 102400;
    bool need2 = (tid + 256 < 400);

    for (int t = 0; t < T; ++t) {
        int xt = d ? (T - 1 - t) : t;
        float xgv = xg[(size_t)xt * 3200 + d * 1600 + gr];
        float* hb = hbuf[t & 1];

        if (t == 0) {
            hb[tid] = h0[(hc_base + d) * 400 + tid];
            if (need2) hb[tid + 256] = h0[(hc_base + d) * 400 + tid + 256];
        } else {
            const u64* src = hst + (size_t)(t - 1) * 400;
            u32 want = tag_base + (u32)t;
            bool d1 = false, d2 = !need2;
            while (!(d1 && d2)) {
                u64 v1 = 0, v2 = 0;
                if (!d1) v1 = __hip_atomic_load(&src[tid], __ATOMIC_RELAXED, __HIP_MEMORY_SCOPE_AGENT);
                if (!d2) v2 = __hip_atomic_load(&src[tid + 256], __ATOMIC_RELAXED, __HIP_MEMORY_SCOPE_AGENT);
                if (!d1 && (u32)(v1 >> 32) == want) { hb[tid] = __uint_as_float((u32)v1); d1 = true; }
                if (!d2 && (u32)(v2 >> 32) == want) { hb[tid + 256] = __uint_as_float((u32)v2); d2 = true; }
            }
        }
        __syncthreads();

        const float4* h4 = (const float4*)hb;
        float s = 0.f;
        #pragma unroll
        for (int i = 0; i < 13; ++i) {
            float4 hv = h4[c + 8 * i];
            s += wv[i].x * hv.x + wv[i].y * hv.y + wv[i].z * hv.z + wv[i].w * hv.w;
        }
        s += __shfl_down(s, 4);
        s += __shfl_down(s, 2);
        s += __shfl_down(s, 1);

        float v = 0.f;
        if (c == 0) {
            float tot = s + xgv;
            float arg = (gate == 2) ? 2.f * tot : -tot;
            arg = fminf(fmaxf(arg, -60.f), 60.f);
            float e = __expf(arg);
            v = (gate == 2) ? (e - 1.f) * __frcp_rn(e + 1.f)
                            : __frcp_rn(1.f + e);
        }
        float fv = __shfl(v, lane + 16);
        float gv = __shfl(v, lane + 32);
        float ov = __shfl(v, lane + 48);
        if (lane == 0 || lane == 8) {
            c_state = fv * c_state + v * gv;
            float ec = __expf(fminf(fmaxf(2.f * c_state, -60.f), 60.f));
            float th = (ec - 1.f) * __frcp_rn(ec + 1.f);
            float h = ov * th;
            u64 pk = (((u64)(tag_base + t + 1)) << 32) | (u64)__float_as_uint(h);
            __hip_atomic_store(&hst[(size_t)t * 400 + a8 + 2 * w + jj], pk,
                               __ATOMIC_RELAXED, __HIP_MEMORY_SCOPE_AGENT);
        }
    }
}

// shared-memory union: GEMM tiles and LSTM hbuf never coexist in one block
union SmemU {
    struct { float As[16][68]; float Bs[16][68]; } g;
    float hbuf[2][416];
};

// ---------------- fused dispatch 2: layer-0 LSTM + layer-1 xg GEMM ----------------
// blocks 0..99: LSTM layer 0.  blocks 100..299: xg1[t][n] = hV0[t] @ Wih1[n] + bih1[n]+bhh1[n]
// (K=800, N=3200), A read via tag-spin so the GEMM overlaps the producing LSTM.
__global__ __launch_bounds__(256)
void lstm0_fused(const float* __restrict__ Whh, const float* __restrict__ h0,
                 const float* __restrict__ c0, const float* __restrict__ xg0,
                 u64* __restrict__ hist,
                 const float* __restrict__ Wih1, const float* __restrict__ bih1,
                 const float* __restrict__ bhh1, float* __restrict__ xg1) {
    __shared__ SmemU sm;
    int bid = blockIdx.x;
    if (bid < 2 * LSTM_G) {
        lstm_body(bid, Whh, h0, c0, 0, xg0, hist, 0u, sm.hbuf);
        return;
    }
    int g = bid - 2 * LSTM_G;
    int t0 = (g & 3) * 64;
    int n0 = (g >> 2) * 64;
    int tid = threadIdx.x;
    int tx = tid & 15, ty = tid >> 4;
    int lr = tid >> 2, lk = (tid & 3) * 4;
    float acc[4][4] = {};
    int t = t0 + lr;

    // fwd half (k<400) ready at step t0+63; bwd half at step 255-t0 -> early half first
    int first = (t0 >= 128) ? 400 : 0;
    for (int seg = 0; seg < 2; ++seg) {
        int kb = first ^ (seg ? 400 : 0);
        for (int k0 = kb; k0 < kb + 400; k0 += 16) {
            float4 av = hist4_spin(hist, t, k0 + lk, 0u);
            float4 bv = *(const float4*)(Wih1 + (size_t)(n0 + lr) * 800 + k0 + lk);
            stage16(sm.g.As, sm.g.Bs, lk, lr, av, bv);
            fma16(acc, sm.g.As, sm.g.Bs, tx, ty);
        }
    }
    float bs[4];
    #pragma unroll
    for (int j = 0; j < 4; ++j) {
        int n = n0 + tx * 4 + j;
        bs[j] = bih1[n] + bhh1[n];
    }
    #pragma unroll
    for (int i = 0; i < 4; ++i) {
        int tr = t0 + ty * 4 + i;
        float4 o;
        o.x = acc[i][0] + bs[0]; o.y = acc[i][1] + bs[1];
        o.z = acc[i][2] + bs[2]; o.w = acc[i][3] + bs[3];
        *(float4*)(xg1 + (size_t)tr * 3200 + n0 + tx * 4) = o;
    }
}

// ---------------- fused dispatch 3: layer-1 LSTM + PQ/U GEMMs ----------------
// blocks 0..99: LSTM layer 1 (tags 257..512).
// blocks 100..199: U tiles (K=1600; cols 800.. gather hV1[head(t)]) -> dispatched before PQ (longer).
// blocks 200..399: PQ tiles (K=800).
__global__ __launch_bounds__(256)
void lstm1_fused(const float* __restrict__ Whh, const float* __restrict__ h0,
                 const float* __restrict__ c0, const float* __restrict__ xg1,
                 u64* __restrict__ hist, const int* __restrict__ arcs,
                 const float* __restrict__ Wa1, const float* __restrict__ ba1,
                 const float* __restrict__ Wl1, const float* __restrict__ bl1,
                 float* __restrict__ PQ, float* __restrict__ U) {
    __shared__ SmemU sm;
    int bid = blockIdx.x;
    if (bid < 2 * LSTM_G) {
        lstm_body(bid, Whh, h0, c0, 2, xg1, hist, 256u, sm.hbuf);
        return;
    }
    int g = bid - 2 * LSTM_G;
    int t0 = (g & 3) * 64;
    int by = g >> 2;                    // 0..74: by<25 -> U tile, else PQ tile
    int tid = threadIdx.x;
    int tx = tid & 15, ty = tid >> 4;
    int lr = tid >> 2, lk = (tid & 3) * 4;
    float acc[4][4] = {};
    int t = t0 + lr;
    int first = (t0 >= 128) ? 400 : 0;  // early-available half of hV[t] first

    if (by < 25) {
        // ---- U path ----
        int n0 = by * 64;
        int h = arcs[1 + t];
        int tind = min(max(h - 1, 0), 255);
        for (int seg = 0; seg < 3; ++seg) {
            int kb   = (seg < 2) ? (first ^ (seg ? 400 : 0)) : 800;
            int klen = (seg < 2) ? 400 : 800;
            for (int k0 = kb; k0 < kb + klen; k0 += 16) {
                int k = k0 + lk;
                float4 av = (k < 800) ? hist4_spin(hist, t, k, 256u)
                                      : hist4_spin(hist, tind, k - 800, 256u);
                float4 bv = *(const float4*)(Wl1 + (size_t)(n0 + lr) * 1600 + k);
                stage16(sm.g.As, sm.g.Bs, lk, lr, av, bv);
                fma16(acc, sm.g.As, sm.g.Bs, tx, ty);
            }
        }
        float bs[4];
        #pragma unroll
        for (int j = 0; j < 4; ++j) bs[j] = bl1[n0 + tx * 4 + j];
        #pragma unroll
        for (int i = 0; i < 4; ++i) {
            int tr = t0 + ty * 4 + i;
            float4 o;
            o.x = fast_tanh(acc[i][0] + bs[0]); o.y = fast_tanh(acc[i][1] + bs[1]);
            o.z = fast_tanh(acc[i][2] + bs[2]); o.w = fast_tanh(acc[i][3] + bs[3]);
            *(float4*)(U + (size_t)tr * 1600 + n0 + tx * 4) = o;
        }
    } else {
        // ---- PQ path ----
        int n0 = (by - 25) * 64;
        int nn = n0 + lr;
        const float* brow = (nn < 1600) ? Wa1 + (size_t)nn * 1600
                                        : Wa1 + (size_t)(nn - 1600) * 1600 + 800;
        for (int seg = 0; seg < 2; ++seg) {
            int kb = first ^ (seg ? 400 : 0);
            for (int k0 = kb; k0 < kb + 400; k0 += 16) {
                float4 av = hist4_spin(hist, t, k0 + lk, 256u);
                float4 bv = *(const float4*)(brow + k0 + lk);
                stage16(sm.g.As, sm.g.Bs, lk, lr, av, bv);
                fma16(acc, sm.g.As, sm.g.Bs, tx, ty);
            }
        }
        float bs[4];
        #pragma unroll
        for (int j = 0; j < 4; ++j) {
            int n = n0 + tx * 4 + j;
            bs[j] = (n < 1600) ? ba1[n] : 0.f;
        }
        #pragma unroll
        for (int i = 0; i < 4; ++i) {
            int tr = t0 + ty * 4 + i;
            float4 o;
            o.x = acc[i][0] + bs[0]; o.y = acc[i][1] + bs[1];
            o.z = acc[i][2] + bs[2]; o.w = acc[i][3] + bs[3];
            *(float4*)(PQ + (size_t)tr * 3200 + n0 + tx * 4) = o;
        }
    }
}

// ---------------- arc pairwise scorer (+ borders, folded in) ----------------
__global__ __launch_bounds__(256)
void arc_kernel(const float* __restrict__ PQ,
                const float* __restrict__ Wa2, const float* __restrict__ ba2,
                float* __restrict__ out) {
    int i0 = blockIdx.x * 16, j0 = blockIdx.y * 16;
    int tid = threadIdx.x;
    int ii = tid >> 4, jj = tid & 15;
    __shared__ float Pt[16][65], Qt[16][65];
    __shared__ float W2f[1600];

    if (i0 == 0 && j0 == 0) {   // borders: row 0 (with [0,0]=1) and col 0
        if (tid < 257) out[tid] = (tid == 0) ? 1.0f : 0.0f;
        out[(size_t)(tid + 1) * 257] = 0.0f;
        if (tid == 0) out[0] = 1.0f;
    }
    for (int m = tid; m < 1600; m += 256) W2f[m] = Wa2[m];
    __syncthreads();

    float acc = 0.f;
    int mm = tid & 63, r4 = tid >> 6;
    for (int m0 = 0; m0 < 1600; m0 += 64) {
        #pragma unroll
        for (int rr = r4; rr < 16; rr += 4) {
            Pt[rr][mm] = PQ[(size_t)(i0 + rr) * 3200 + m0 + mm];
            Qt[rr][mm] = PQ[(size_t)(j0 + rr) * 3200 + 1600 + m0 + mm];
        }
        __syncthreads();
        #pragma unroll 8
        for (int m = 0; m < 64; ++m) {
            float s = Pt[ii][m] + Qt[jj][m];
            acc += W2f[m0 + m] * fast_tanh(s);
        }
        __syncthreads();
    }
    float raw = acc + ba2[0];
    int gi = i0 + ii, gj = j0 + jj;
    if (gi == gj) raw = 0.f;
    out[(size_t)(gi + 1) * 257 + (gj + 1)] = raw;
}

// ---------------- label output ----------------
__global__ __launch_bounds__(256)
void label_out_kernel(const float* __restrict__ U, const float* __restrict__ Wl2,
                      const float* __restrict__ bl2, const int* __restrict__ arcs,
                      float* __restrict__ out) {
    int t = blockIdx.x;
    __shared__ float u_l[1600];
    __shared__ float part[4][64];
    for (int m = threadIdx.x; m < 1600; m += 256) u_l[m] = U[(size_t)t * 1600 + m];
    __syncthreads();
    int tid = threadIdx.x;
    int n = tid & 63, p = tid >> 6;
    float acc = 0.f;
    if (n < 40) {
        const float4* wr4 = (const float4*)(Wl2 + (size_t)n * 1600 + p * 400);
        const float*  ub  = u_l + p * 400;
        for (int m = 0; m < 100; ++m) {
            float4 w = wr4[m];
            acc += ub[4*m] * w.x + ub[4*m+1] * w.y + ub[4*m+2] * w.z + ub[4*m+3] * w.w;
        }
    }
    part[p][n] = acc;
    __syncthreads();
    if (tid < 40) {
        float v = part[0][tid] + part[1][tid] + part[2][tid] + part[3][tid] + bl2[tid];
        if (arcs[1 + t] == 0) v = 0.f;
        out[(size_t)t * 40 + tid] = v;
    }
}

// ---------------- launch ----------------
extern "C" void kernel_launch(void* const* d_in, const int* in_sizes, int n_in,
                              void* d_out, int out_size, void* d_ws, size_t ws_size,
                              hipStream_t stream) {
    const int*   words = (const int*)d_in[0];
    const int*   tags  = (const int*)d_in[1];
    const int*   arcs  = (const int*)d_in[2];
    const float* h0    = (const float*)d_in[3];
    const float* c0    = (const float*)d_in[4];
    const float* wemb  = (const float*)d_in[5];
    const float* temb  = (const float*)d_in[6];
    const float* Wih0  = (const float*)d_in[7];
    const float* Whh0  = (const float*)d_in[8];
    const float* bih0  = (const float*)d_in[9];
    const float* bhh0  = (const float*)d_in[10];
    const float* Wih1  = (const float*)d_in[11];
    const float* Whh1  = (const float*)d_in[12];
    const float* bih1  = (const float*)d_in[13];
    const float* bhh1  = (const float*)d_in[14];
    const float* Wa1   = (const float*)d_in[15];
    const float* ba1   = (const float*)d_in[16];
    const float* Wa2   = (const float*)d_in[17];
    const float* ba2   = (const float*)d_in[18];
    const float* Wl1   = (const float*)d_in[19];
    const float* bl1   = (const float*)d_in[20];
    const float* Wl2   = (const float*)d_in[21];
    const float* bl2   = (const float*)d_in[22];
    float* out = (float*)d_out;

    char* ws = (char*)d_ws;
    float* xg0  = (float*)(ws + OF_XG);   // layer-0 gates; region reused for PQ afterwards
    u64*   hist = (u64*)  (ws + OF_H);
    float* xg1  = (float*)(ws + OF_PQ);   // layer-1 gates live where PQ used to
    float* PQ   = (float*)(ws + OF_XG);   // PQ overwrites dead xg0
    float* U    = (float*)(ws + OF_U);

    gemm_embed_kernel<<<dim3(4, 50), 256, 0, stream>>>(words, tags, wemb, temb, Wih0, bih0, bhh0, xg0);
    lstm0_fused<<<300, 256, 0, stream>>>(Whh0, h0, c0, xg0, hist, Wih1, bih1, bhh1, xg1);
    lstm1_fused<<<400, 256, 0, stream>>>(Whh1, h0, c0, xg1, hist, arcs, Wa1, ba1, Wl1, bl1, PQ, U);
    arc_kernel<<<dim3(16, 16), 256, 0, stream>>>(PQ, Wa2, ba2, out);
    label_out_kernel<<<256, 256, 0, stream>>>(U, Wl2, bl2, arcs, out + 66049);
}

// Round 4
// 1173.990 us; speedup vs baseline: 1.0775x; 1.0775x over previous
//
#include <hip/hip_runtime.h>

typedef unsigned int   u32;
typedef unsigned long long u64;

// ---------------- helpers ----------------
__device__ __forceinline__ float fast_tanh(float x) {
    x = fminf(fmaxf(x, -15.f), 15.f);
    float e = __expf(2.f * x);
    return __fdividef(e - 1.f, e + 1.f);
}

// ---------------- workspace layout (bytes, all fp32) ----------------
// OF_XG: xg0 (layer-0 gates), later reused for PQ.  OF_PQ: xg1 (layer-1 gates).
// hist: 2x256x400 u64 tag-versioned (reused by both layers, disjoint tag ranges).
#define OF_XG   ((size_t)0)
#define OF_H    (OF_XG + 3276800)
#define OF_PQ   (OF_H  + 1638400)
#define OF_U    (OF_PQ + 3276800)

// ---- tag-verified hist read: fast path is load+compare; spin only on rare miss ----
// layer tag ranges: layer0 base=0 -> tags 1..256; layer1 base=256 -> tags 257..512.
__device__ __forceinline__ float4 hist4_spin(const u64* __restrict__ hist, int t, int k, u32 base) {
    const u64* p; u32 want;
    if (k < 400) { p = hist + (size_t)t * 400 + k;                        want = base + (u32)t + 1u; }
    else         { p = hist + 102400 + (size_t)(255 - t) * 400 + (k - 400); want = base + (u32)(255 - t) + 1u; }
    for (;;) {
        u64 a = __hip_atomic_load(p + 0, __ATOMIC_RELAXED, __HIP_MEMORY_SCOPE_AGENT);
        u64 b = __hip_atomic_load(p + 1, __ATOMIC_RELAXED, __HIP_MEMORY_SCOPE_AGENT);
        u64 c = __hip_atomic_load(p + 2, __ATOMIC_RELAXED, __HIP_MEMORY_SCOPE_AGENT);
        u64 d = __hip_atomic_load(p + 3, __ATOMIC_RELAXED, __HIP_MEMORY_SCOPE_AGENT);
        if ((u32)(a >> 32) == want && (u32)(b >> 32) == want &&
            (u32)(c >> 32) == want && (u32)(d >> 32) == want)
            return make_float4(__uint_as_float((u32)a), __uint_as_float((u32)b),
                               __uint_as_float((u32)c), __uint_as_float((u32)d));
        __builtin_amdgcn_s_sleep(8);    // short: post-gate misses are brief
    }
}

// ---- block-level gate: ONE thread polls two sample words of the gating row ----
// (entries 0 and 399 come from producer blocks 0 and 49 -> samples dispatch spread);
// everyone else sleeps at the barrier. Poll period ~0.4us -> negligible fabric traffic.
__device__ __forceinline__ void gate_wait(const u64* __restrict__ w0, const u64* __restrict__ w1,
                                          u32 want0, u32 want1) {
    if (threadIdx.x == 0) {
        for (;;) {
            u32 g0 = (u32)(__hip_atomic_load(w0, __ATOMIC_RELAXED, __HIP_MEMORY_SCOPE_AGENT) >> 32);
            u32 g1 = (u32)(__hip_atomic_load(w1, __ATOMIC_RELAXED, __HIP_MEMORY_SCOPE_AGENT) >> 32);
            if (g0 == want0 && g1 == want1) break;
            __builtin_amdgcn_s_sleep(16);
        }
    }
    __syncthreads();
}

// ---- shared GEMM micro-kernel pieces (64x64 tile, 16-deep K step) ----
__device__ __forceinline__ void stage16(float (*As)[68], float (*Bs)[68],
                                        int lk, int lr, float4 av, float4 bv) {
    __syncthreads();
    As[lk + 0][lr] = av.x; As[lk + 1][lr] = av.y; As[lk + 2][lr] = av.z; As[lk + 3][lr] = av.w;
    Bs[lk + 0][lr] = bv.x; Bs[lk + 1][lr] = bv.y; Bs[lk + 2][lr] = bv.z; Bs[lk + 3][lr] = bv.w;
    __syncthreads();
}

__device__ __forceinline__ void fma16(float acc[4][4], const float (*As)[68], const float (*Bs)[68],
                                      int tx, int ty) {
    #pragma unroll
    for (int kk = 0; kk < 16; ++kk) {
        float4 a4 = *(const float4*)&As[kk][ty * 4];
        float4 b4 = *(const float4*)&Bs[kk][tx * 4];
        acc[0][0] += a4.x * b4.x; acc[0][1] += a4.x * b4.y; acc[0][2] += a4.x * b4.z; acc[0][3] += a4.x * b4.w;
        acc[1][0] += a4.y * b4.x; acc[1][1] += a4.y * b4.y; acc[1][2] += a4.y * b4.z; acc[1][3] += a4.y * b4.w;
        acc[2][0] += a4.z * b4.x; acc[2][1] += a4.z * b4.y; acc[2][2] += a4.z * b4.z; acc[2][3] += a4.z * b4.w;
        acc[3][0] += a4.w * b4.x; acc[3][1] += a4.w * b4.y; acc[3][2] += a4.w * b4.z; acc[3][3] += a4.w * b4.w;
    }
}

// ---------------- GEMM with A gathered from embeddings (layer-0 xg) ----------------
__global__ __launch_bounds__(256)
void gemm_embed_kernel(const int* __restrict__ words, const int* __restrict__ tags,
                       const float* __restrict__ wemb, const float* __restrict__ temb,
                       const float* __restrict__ B,
                       const float* __restrict__ bias1, const float* __restrict__ bias2,
                       float* __restrict__ C) {
    int t0 = blockIdx.x * 64;
    int n0 = blockIdx.y * 64;
    int tid = threadIdx.x;
    int tx = tid & 15, ty = tid >> 4;
    int lr = tid >> 2, lk = (tid & 3) * 4;
    __shared__ float As[16][68];
    __shared__ float Bs[16][68];
    float acc[4][4] = {};

    int t = t0 + lr;
    const float* arow0 = wemb + (size_t)words[t] * 300;
    const float* arow1 = temb + (size_t)tags[t] * 100 - 300;   // indexed by k directly

    for (int k0 = 0; k0 < 400; k0 += 16) {
        int k = k0 + lk;   // 300 % 4 == 0, so each float4 stays in one table
        float4 av = (k < 300) ? *(const float4*)(arow0 + k) : *(const float4*)(arow1 + k);
        float4 bv = *(const float4*)(B + (size_t)(n0 + lr) * 400 + k);
        stage16(As, Bs, lk, lr, av, bv);
        fma16(acc, As, Bs, tx, ty);
    }
    float bs[4];
    #pragma unroll
    for (int j = 0; j < 4; ++j) {
        int n = n0 + tx * 4 + j;
        bs[j] = bias1[n] + bias2[n];
    }
    #pragma unroll
    for (int i = 0; i < 4; ++i) {
        int tr = t0 + ty * 4 + i;
        float4 o;
        o.x = acc[i][0] + bs[0]; o.y = acc[i][1] + bs[1];
        o.z = acc[i][2] + bs[2]; o.w = acc[i][3] + bs[3];
        *(float4*)(C + (size_t)tr * 3200 + n0 + tx * 4) = o;
    }
}

// ---------------- persistent distributed LSTM body (exact R4 logic) ----------------
#define LSTM_G 50
__device__ __forceinline__ void lstm_body(int bid,
                 const float* __restrict__ Whh,   // (2,1600,400)
                 const float* __restrict__ h0,    // (4,400)
                 const float* __restrict__ c0,    // (4,400)
                 int hc_base,
                 const float* __restrict__ xg,    // (256,3200): [t][d*1600 + gaterow]
                 u64* __restrict__ hist,          // (2,256,400)
                 u32 tag_base,
                 float (*hbuf)[416]) {
    const int T = 256;
    int d  = bid / LSTM_G;
    int wg = bid % LSTM_G;
    int a8 = wg * 8;
    int tid = threadIdx.x;
    int w = tid >> 6, lane = tid & 63;
    int c = lane & 7, r = lane >> 3;
    int gate = r >> 1, jj = r & 1;
    int gr = gate * 400 + a8 + 2 * w + jj;

    float4 wv[13];
    const float* wrow = Whh + (size_t)d * 640000 + (size_t)gr * 400;
    #pragma unroll
    for (int i = 0; i < 13; ++i) {
        int k = 4 * (c + 8 * i);
        wv[i] = (k + 3 < 400) ? *(const float4*)(wrow + k) : make_float4(0.f, 0.f, 0.f, 0.f);
    }
    if (tid < 16) { hbuf[0][400 + tid] = 0.f; hbuf[1][400 + tid] = 0.f; }

    float c_state = 0.f;
    if (lane == 0 || lane == 8)
        c_state = c0[(hc_base + d) * 400 + a8 + 2 * w + jj];

    u64* hst = hist + (size_t)d * 102400;
    bool need2 = (tid + 256 < 400);

    for (int t = 0; t < T; ++t) {
        int xt = d ? (T - 1 - t) : t;
        float xgv = xg[(size_t)xt * 3200 + d * 1600 + gr];
        float* hb = hbuf[t & 1];

        if (t == 0) {
            hb[tid] = h0[(hc_base + d) * 400 + tid];
            if (need2) hb[tid + 256] = h0[(hc_base + d) * 400 + tid + 256];
        } else {
            const u64* src = hst + (size_t)(t - 1) * 400;
            u32 want = tag_base + (u32)t;
            bool d1 = false, d2 = !need2;
            while (!(d1 && d2)) {
                u64 v1 = 0, v2 = 0;
                if (!d1) v1 = __hip_atomic_load(&src[tid], __ATOMIC_RELAXED, __HIP_MEMORY_SCOPE_AGENT);
                if (!d2) v2 = __hip_atomic_load(&src[tid + 256], __ATOMIC_RELAXED, __HIP_MEMORY_SCOPE_AGENT);
                if (!d1 && (u32)(v1 >> 32) == want) { hb[tid] = __uint_as_float((u32)v1); d1 = true; }
                if (!d2 && (u32)(v2 >> 32) == want) { hb[tid + 256] = __uint_as_float((u32)v2); d2 = true; }
            }
        }
        __syncthreads();

        const float4* h4 = (const float4*)hb;
        float s = 0.f;
        #pragma unroll
        for (int i = 0; i < 13; ++i) {
            float4 hv = h4[c + 8 * i];
            s += wv[i].x * hv.x + wv[i].y * hv.y + wv[i].z * hv.z + wv[i].w * hv.w;
        }
        s += __shfl_down(s, 4);
        s += __shfl_down(s, 2);
        s += __shfl_down(s, 1);

        float v = 0.f;
        if (c == 0) {
            float tot = s + xgv;
            float arg = (gate == 2) ? 2.f * tot : -tot;
            arg = fminf(fmaxf(arg, -60.f), 60.f);
            float e = __expf(arg);
            v = (gate == 2) ? (e - 1.f) * __frcp_rn(e + 1.f)
                            : __frcp_rn(1.f + e);
        }
        float fv = __shfl(v, lane + 16);
        float gv = __shfl(v, lane + 32);
        float ov = __shfl(v, lane + 48);
        if (lane == 0 || lane == 8) {
            c_state = fv * c_state + v * gv;
            float ec = __expf(fminf(fmaxf(2.f * c_state, -60.f), 60.f));
            float th = (ec - 1.f) * __frcp_rn(ec + 1.f);
            float h = ov * th;
            u64 pk = (((u64)(tag_base + t + 1)) << 32) | (u64)__float_as_uint(h);
            __hip_atomic_store(&hst[(size_t)t * 400 + a8 + 2 * w + jj], pk,
                               __ATOMIC_RELAXED, __HIP_MEMORY_SCOPE_AGENT);
        }
    }
}

// shared-memory union: GEMM tiles and LSTM hbuf never coexist in one block
union SmemU {
    struct { float As[16][68]; float Bs[16][68]; } g;
    float hbuf[2][416];
};

// ---------------- fused dispatch 2: layer-0 LSTM + layer-1 xg GEMM ----------------
// blocks 0..99: LSTM layer 0.  blocks 100..299: xg1[t][n] = hV0[t] @ Wih1[n] + bih1[n]+bhh1[n]
// (K=800, N=3200). Each K-segment is gated block-wide (single waiter) on the LAST row it
// needs, then streams at full speed; per-load tag-verify remains as the correctness net.
__global__ __launch_bounds__(256)
void lstm0_fused(const float* __restrict__ Whh, const float* __restrict__ h0,
                 const float* __restrict__ c0, const float* __restrict__ xg0,
                 u64* __restrict__ hist,
                 const float* __restrict__ Wih1, const float* __restrict__ bih1,
                 const float* __restrict__ bhh1, float* __restrict__ xg1) {
    __shared__ SmemU sm;
    int bid = blockIdx.x;
    if (bid < 2 * LSTM_G) {
        lstm_body(bid, Whh, h0, c0, 0, xg0, hist, 0u, sm.hbuf);
        return;
    }
    int g = bid - 2 * LSTM_G;
    int t0 = (g & 3) * 64;
    int n0 = (g >> 2) * 64;
    int tid = threadIdx.x;
    int tx = tid & 15, ty = tid >> 4;
    int lr = tid >> 2, lk = (tid & 3) * 4;
    float acc[4][4] = {};
    int t = t0 + lr;

    // fwd half (k<400) ready at step t0+63; bwd half at step 255-t0 -> early half first
    int first = (t0 >= 128) ? 400 : 0;
    for (int seg = 0; seg < 2; ++seg) {
        int kb = first ^ (seg ? 400 : 0);
        if (kb == 0) {      // fwd rows t0..t0+63: last produced at fwd step t0+63
            const u64* gw = hist + (size_t)(t0 + 63) * 400;
            gate_wait(gw, gw + 399, (u32)(t0 + 64), (u32)(t0 + 64));
        } else {            // bwd slots 255-t, max slot = 255-t0 (for row t0)
            const u64* gw = hist + 102400 + (size_t)(255 - t0) * 400;
            gate_wait(gw, gw + 399, (u32)(256 - t0), (u32)(256 - t0));
        }
        for (int k0 = kb; k0 < kb + 400; k0 += 16) {
            float4 av = hist4_spin(hist, t, k0 + lk, 0u);
            float4 bv = *(const float4*)(Wih1 + (size_t)(n0 + lr) * 800 + k0 + lk);
            stage16(sm.g.As, sm.g.Bs, lk, lr, av, bv);
            fma16(acc, sm.g.As, sm.g.Bs, tx, ty);
        }
    }
    float bs[4];
    #pragma unroll
    for (int j = 0; j < 4; ++j) {
        int n = n0 + tx * 4 + j;
        bs[j] = bih1[n] + bhh1[n];
    }
    #pragma unroll
    for (int i = 0; i < 4; ++i) {
        int tr = t0 + ty * 4 + i;
        float4 o;
        o.x = acc[i][0] + bs[0]; o.y = acc[i][1] + bs[1];
        o.z = acc[i][2] + bs[2]; o.w = acc[i][3] + bs[3];
        *(float4*)(xg1 + (size_t)tr * 3200 + n0 + tx * 4) = o;
    }
}

// ---------------- fused dispatch 3: layer-1 LSTM + PQ/U GEMMs ----------------
// blocks 0..99: LSTM layer 1 (tags 257..512).
// blocks 100..199: U tiles (K=1600; cols 800.. gather hV1[head(t)]) -> dispatched before PQ.
// blocks 200..399: PQ tiles (K=800).  All segments gated (single waiter).
__global__ __launch_bounds__(256)
void lstm1_fused(const float* __restrict__ Whh, const float* __restrict__ h0,
                 const float* __restrict__ c0, const float* __restrict__ xg1,
                 u64* __restrict__ hist, const int* __restrict__ arcs,
                 const float* __restrict__ Wa1, const float* __restrict__ ba1,
                 const float* __restrict__ Wl1, const float* __restrict__ bl1,
                 float* __restrict__ PQ, float* __restrict__ U) {
    __shared__ SmemU sm;
    int bid = blockIdx.x;
    if (bid < 2 * LSTM_G) {
        lstm_body(bid, Whh, h0, c0, 2, xg1, hist, 256u, sm.hbuf);
        return;
    }
    int g = bid - 2 * LSTM_G;
    int t0 = (g & 3) * 64;
    int by = g >> 2;                    // 0..74: by<25 -> U tile, else PQ tile
    int tid = threadIdx.x;
    int tx = tid & 15, ty = tid >> 4;
    int lr = tid >> 2, lk = (tid & 3) * 4;
    float acc[4][4] = {};
    int t = t0 + lr;
    int first = (t0 >= 128) ? 400 : 0;  // early-available half of hV[t] first

    if (by < 25) {
        // ---- U path ----
        int n0 = by * 64;
        int h = arcs[1 + t];
        int tind = min(max(h - 1, 0), 255);
        for (int seg = 0; seg < 3; ++seg) {
            int kb   = (seg < 2) ? (first ^ (seg ? 400 : 0)) : 800;
            int klen = (seg < 2) ? 400 : 800;
            if (seg < 2) {
                if (kb == 0) {
                    const u64* gw = hist + (size_t)(t0 + 63) * 400;
                    gate_wait(gw, gw + 399, (u32)(t0 + 320), (u32)(t0 + 320));
                } else {
                    const u64* gw = hist + 102400 + (size_t)(255 - t0) * 400;
                    gate_wait(gw, gw + 399, (u32)(512 - t0), (u32)(512 - t0));
                }
            } else {        // head gather: arbitrary rows -> need both directions complete
                const u64* gf = hist + (size_t)255 * 400;
                const u64* gb = hist + 102400 + (size_t)255 * 400;
                gate_wait(gf, gb, 512u, 512u);
            }
            for (int k0 = kb; k0 < kb + klen; k0 += 16) {
                int k = k0 + lk;
                float4 av = (k < 800) ? hist4_spin(hist, t, k, 256u)
                                      : hist4_spin(hist, tind, k - 800, 256u);
                float4 bv = *(const float4*)(Wl1 + (size_t)(n0 + lr) * 1600 + k);
                stage16(sm.g.As, sm.g.Bs, lk, lr, av, bv);
                fma16(acc, sm.g.As, sm.g.Bs, tx, ty);
            }
        }
        float bs[4];
        #pragma unroll
        for (int j = 0; j < 4; ++j) bs[j] = bl1[n0 + tx * 4 + j];
        #pragma unroll
        for (int i = 0; i < 4; ++i) {
            int tr = t0 + ty * 4 + i;
            float4 o;
            o.x = fast_tanh(acc[i][0] + bs[0]); o.y = fast_tanh(acc[i][1] + bs[1]);
            o.z = fast_tanh(acc[i][2] + bs[2]); o.w = fast_tanh(acc[i][3] + bs[3]);
            *(float4*)(U + (size_t)tr * 1600 + n0 + tx * 4) = o;
        }
    } else {
        // ---- PQ path ----
        int n0 = (by - 25) * 64;
        int nn = n0 + lr;
        const float* brow = (nn < 1600) ? Wa1 + (size_t)nn * 1600
                                        : Wa1 + (size_t)(nn - 1600) * 1600 + 800;
        for (int seg = 0; seg < 2; ++seg) {
            int kb = first ^ (seg ? 400 : 0);
            if (kb == 0) {
                const u64* gw = hist + (size_t)(t0 + 63) * 400;
                gate_wait(gw, gw + 399, (u32)(t0 + 320), (u32)(t0 + 320));
            } else {
                const u64* gw = hist + 102400 + (size_t)(255 - t0) * 400;
                gate_wait(gw, gw + 399, (u32)(512 - t0), (u32)(512 - t0));
            }
            for (int k0 = kb; k0 < kb + 400; k0 += 16) {
                float4 av = hist4_spin(hist, t, k0 + lk, 256u);
                float4 bv = *(const float4*)(brow + k0 + lk);
                stage16(sm.g.As, sm.g.Bs, lk, lr, av, bv);
                fma16(acc, sm.g.As, sm.g.Bs, tx, ty);
            }
        }
        float bs[4];
        #pragma unroll
        for (int j = 0; j < 4; ++j) {
            int n = n0 + tx * 4 + j;
            bs[j] = (n < 1600) ? ba1[n] : 0.f;
        }
        #pragma unroll
        for (int i = 0; i < 4; ++i) {
            int tr = t0 + ty * 4 + i;
            float4 o;
            o.x = acc[i][0] + bs[0]; o.y = acc[i][1] + bs[1];
            o.z = acc[i][2] + bs[2]; o.w = acc[i][3] + bs[3];
            *(float4*)(PQ + (size_t)tr * 3200 + n0 + tx * 4) = o;
        }
    }
}

// ---------------- arc pairwise scorer (+ borders, folded in) ----------------
__global__ __launch_bounds__(256)
void arc_kernel(const float* __restrict__ PQ,
                const float* __restrict__ Wa2, const float* __restrict__ ba2,
                float* __restrict__ out) {
    int i0 = blockIdx.x * 16, j0 = blockIdx.y * 16;
    int tid = threadIdx.x;
    int ii = tid >> 4, jj = tid & 15;
    __shared__ float Pt[16][65], Qt[16][65];
    __shared__ float W2f[1600];

    if (i0 == 0 && j0 == 0) {   // borders: row 0 (with [0,0]=1) and col 0
        if (tid < 257) out[tid] = (tid == 0) ? 1.0f : 0.0f;
        out[(size_t)(tid + 1) * 257] = 0.0f;
        if (tid == 0) out[0] = 1.0f;
    }
    for (int m = tid; m < 1600; m += 256) W2f[m] = Wa2[m];
    __syncthreads();

    float acc = 0.f;
    int mm = tid & 63, r4 = tid >> 6;
    for (int m0 = 0; m0 < 1600; m0 += 64) {
        #pragma unroll
        for (int rr = r4; rr < 16; rr += 4) {
            Pt[rr][mm] = PQ[(size_t)(i0 + rr) * 3200 + m0 + mm];
            Qt[rr][mm] = PQ[(size_t)(j0 + rr) * 3200 + 1600 + m0 + mm];
        }
        __syncthreads();
        #pragma unroll 8
        for (int m = 0; m < 64; ++m) {
            float s = Pt[ii][m] + Qt[jj][m];
            acc += W2f[m0 + m] * fast_tanh(s);
        }
        __syncthreads();
    }
    float raw = acc + ba2[0];
    int gi = i0 + ii, gj = j0 + jj;
    if (gi == gj) raw = 0.f;
    out[(size_t)(gi + 1) * 257 + (gj + 1)] = raw;
}

// ---------------- label output ----------------
__global__ __launch_bounds__(256)
void label_out_kernel(const float* __restrict__ U, const float* __restrict__ Wl2,
                      const float* __restrict__ bl2, const int* __restrict__ arcs,
                      float* __restrict__ out) {
    int t = blockIdx.x;
    __shared__ float u_l[1600];
    __shared__ float part[4][64];
    for (int m = threadIdx.x; m < 1600; m += 256) u_l[m] = U[(size_t)t * 1600 + m];
    __syncthreads();
    int tid = threadIdx.x;
    int n = tid & 63, p = tid >> 6;
    float acc = 0.f;
    if (n < 40) {
        const float4* wr4 = (const float4*)(Wl2 + (size_t)n * 1600 + p * 400);
        const float*  ub  = u_l + p * 400;
        for (int m = 0; m < 100; ++m) {
            float4 w = wr4[m];
            acc += ub[4*m] * w.x + ub[4*m+1] * w.y + ub[4*m+2] * w.z + ub[4*m+3] * w.w;
        }
    }
    part[p][n] = acc;
    __syncthreads();
    if (tid < 40) {
        float v = part[0][tid] + part[1][tid] + part[2][tid] + part[3][tid] + bl2[tid];
        if (arcs[1 + t] == 0) v = 0.f;
        out[(size_t)t * 40 + tid] = v;
    }
}

// ---------------- launch ----------------
extern "C" void kernel_launch(void* const* d_in, const int* in_sizes, int n_in,
                              void* d_out, int out_size, void* d_ws, size_t ws_size,
                              hipStream_t stream) {
    const int*   words = (const int*)d_in[0];
    const int*   tags  = (const int*)d_in[1];
    const int*   arcs  = (const int*)d_in[2];
    const float* h0    = (const float*)d_in[3];
    const float* c0    = (const float*)d_in[4];
    const float* wemb  = (const float*)d_in[5];
    const float* temb  = (const float*)d_in[6];
    const float* Wih0  = (const float*)d_in[7];
    const float* Whh0  = (const float*)d_in[8];
    const float* bih0  = (const float*)d_in[9];
    const float* bhh0  = (const float*)d_in[10];
    const float* Wih1  = (const float*)d_in[11];
    const float* Whh1  = (const float*)d_in[12];
    const float* bih1  = (const float*)d_in[13];
    const float* bhh1  = (const float*)d_in[14];
    const float* Wa1   = (const float*)d_in[15];
    const float* ba1   = (const float*)d_in[16];
    const float* Wa2   = (const float*)d_in[17];
    const float* ba2   = (const float*)d_in[18];
    const float* Wl1   = (const float*)d_in[19];
    const float* bl1   = (const float*)d_in[20];
    const float* Wl2   = (const float*)d_in[21];
    const float* bl2   = (const float*)d_in[22];
    float* out = (float*)d_out;

    char* ws = (char*)d_ws;
    float* xg0  = (float*)(ws + OF_XG);   // layer-0 gates; region reused for PQ afterwards
    u64*   hist = (u64*)  (ws + OF_H);
    float* xg1  = (float*)(ws + OF_PQ);   // layer-1 gates live where PQ used to
    float* PQ   = (float*)(ws + OF_XG);   // PQ overwrites dead xg0
    float* U    = (float*)(ws + OF_U);

    gemm_embed_kernel<<<dim3(4, 50), 256, 0, stream>>>(words, tags, wemb, temb, Wih0, bih0, bhh0, xg0);
    lstm0_fused<<<300, 256, 0, stream>>>(Whh0, h0, c0, xg0, hist, Wih1, bih1, bhh1, xg1);
    lstm1_fused<<<400, 256, 0, stream>>>(Whh1, h0, c0, xg1, hist, arcs, Wa1, ba1, Wl1, bl1, PQ, U);
    arc_kernel<<<dim3(16, 16), 256, 0, stream>>>(PQ, Wa2, ba2, out);
    label_out_kernel<<<256, 256, 0, stream>>>(U, Wl2, bl2, arcs, out + 66049);
}

// Round 5
// 1138.907 us; speedup vs baseline: 1.1106x; 1.0308x over previous
//
#include <hip/hip_runtime.h>

typedef unsigned int   u32;
typedef unsigned long long u64;

// ---------------- helpers ----------------
__device__ __forceinline__ float fast_tanh(float x) {
    x = fminf(fmaxf(x, -15.f), 15.f);
    float e = __expf(2.f * x);
    return __fdividef(e - 1.f, e + 1.f);
}

#define HLD(p) __hip_atomic_load((p), __ATOMIC_RELAXED, __HIP_MEMORY_SCOPE_AGENT)

// ---------------- workspace layout (bytes, all fp32) ----------------
// OF_XG: xg0 (layer-0 gates), later reused for PQ.  OF_PQ: xg1 (layer-1 gates).
// hist: 2x256x400 u64 tag-versioned (reused by both layers, disjoint tag ranges).
#define OF_XG   ((size_t)0)
#define OF_H    (OF_XG + 3276800)
#define OF_PQ   (OF_H  + 1638400)
#define OF_U    (OF_PQ + 3276800)

// ---- pipelined tag-verified hist read: issue early, verify at consume ----
// layer tag ranges: layer0 base=0 -> tags 1..256; layer1 base=256 -> tags 257..512.
struct H4 { u64 v0, v1, v2, v3; const u64* p; u32 want; };

__device__ __forceinline__ H4 h4_issue(const u64* __restrict__ hist, int t, int k, u32 base) {
    H4 h;
    if (k < 400) { h.p = hist + (size_t)t * 400 + k;                          h.want = base + (u32)t + 1u; }
    else         { h.p = hist + 102400 + (size_t)(255 - t) * 400 + (k - 400); h.want = base + (u32)(255 - t) + 1u; }
    h.v0 = HLD(h.p + 0); h.v1 = HLD(h.p + 1); h.v2 = HLD(h.p + 2); h.v3 = HLD(h.p + 3);
    return h;
}

__device__ __forceinline__ float4 h4_fin(H4 h) {
    while ((u32)(h.v0 >> 32) != h.want || (u32)(h.v1 >> 32) != h.want ||
           (u32)(h.v2 >> 32) != h.want || (u32)(h.v3 >> 32) != h.want) {
        __builtin_amdgcn_s_sleep(4);    // rare: post-gate miss only
        h.v0 = HLD(h.p + 0); h.v1 = HLD(h.p + 1); h.v2 = HLD(h.p + 2); h.v3 = HLD(h.p + 3);
    }
    return make_float4(__uint_as_float((u32)h.v0), __uint_as_float((u32)h.v1),
                       __uint_as_float((u32)h.v2), __uint_as_float((u32)h.v3));
}

// ---- block-level gate: ONE thread polls two sample words of the gating row ----
__device__ __forceinline__ void gate_wait(const u64* __restrict__ w0, const u64* __restrict__ w1,
                                          u32 want0, u32 want1) {
    if (threadIdx.x == 0) {
        for (;;) {
            u32 g0 = (u32)(HLD(w0) >> 32);
            u32 g1 = (u32)(HLD(w1) >> 32);
            if (g0 == want0 && g1 == want1) break;
            __builtin_amdgcn_s_sleep(16);
        }
    }
    __syncthreads();
}

// ---- GEMM micro-kernel pieces (64x64 tile, 16-deep K step, double-buffered LDS) ----
__device__ __forceinline__ void stage_nb(float (*As)[68], float (*Bs)[68],
                                         int lk, int lr, float4 av, float4 bv) {
    As[lk + 0][lr] = av.x; As[lk + 1][lr] = av.y; As[lk + 2][lr] = av.z; As[lk + 3][lr] = av.w;
    Bs[lk + 0][lr] = bv.x; Bs[lk + 1][lr] = bv.y; Bs[lk + 2][lr] = bv.z; Bs[lk + 3][lr] = bv.w;
}

__device__ __forceinline__ void fma16(float acc[4][4], const float (*As)[68], const float (*Bs)[68],
                                      int tx, int ty) {
    #pragma unroll
    for (int kk = 0; kk < 16; ++kk) {
        float4 a4 = *(const float4*)&As[kk][ty * 4];
        float4 b4 = *(const float4*)&Bs[kk][tx * 4];
        acc[0][0] += a4.x * b4.x; acc[0][1] += a4.x * b4.y; acc[0][2] += a4.x * b4.z; acc[0][3] += a4.x * b4.w;
        acc[1][0] += a4.y * b4.x; acc[1][1] += a4.y * b4.y; acc[1][2] += a4.y * b4.z; acc[1][3] += a4.y * b4.w;
        acc[2][0] += a4.z * b4.x; acc[2][1] += a4.z * b4.y; acc[2][2] += a4.z * b4.z; acc[2][3] += a4.z * b4.w;
        acc[3][0] += a4.w * b4.x; acc[3][1] += a4.w * b4.y; acc[3][2] += a4.w * b4.z; acc[3][3] += a4.w * b4.w;
    }
}

// one K-segment of a hist-consuming GEMM, software-pipelined one step deep.
// A[t'][k'] from tagged hist (t'=t for k<800 else tind, k'=k%800); B row = brow + k.
__device__ __forceinline__ void gemm_seg(float (*AsB)[16][68], float (*BsB)[16][68],
        float acc[4][4], const u64* __restrict__ hist, int t, int tind, u32 base,
        const float* __restrict__ brow, int kb, int klen,
        int lk, int lr, int tx, int ty, int& pb)
{
    int ka = kb + lk;
    H4 h = h4_issue(hist, ka < 800 ? t : tind, ka < 800 ? ka : ka - 800, base);
    float4 bv = *(const float4*)(brow + ka);
    for (int k0 = kb; k0 < kb + klen; k0 += 16) {
        float4 av = h4_fin(h);
        stage_nb(AsB[pb], BsB[pb], lk, lr, av, bv);
        int kn = k0 + 16;
        if (kn < kb + klen) {
            int k2 = kn + lk;
            h  = h4_issue(hist, k2 < 800 ? t : tind, k2 < 800 ? k2 : k2 - 800, base);
            bv = *(const float4*)(brow + k2);
        }
        __syncthreads();                 // single barrier per K-step (double buffer)
        fma16(acc, AsB[pb], BsB[pb], tx, ty);
        pb ^= 1;
    }
}

// ---------------- GEMM with A gathered from embeddings (layer-0 xg) ----------------
__global__ __launch_bounds__(256)
void gemm_embed_kernel(const int* __restrict__ words, const int* __restrict__ tags,
                       const float* __restrict__ wemb, const float* __restrict__ temb,
                       const float* __restrict__ B,
                       const float* __restrict__ bias1, const float* __restrict__ bias2,
                       float* __restrict__ C) {
    int t0 = blockIdx.x * 64;
    int n0 = blockIdx.y * 64;
    int tid = threadIdx.x;
    int tx = tid & 15, ty = tid >> 4;
    int lr = tid >> 2, lk = (tid & 3) * 4;
    __shared__ float As[2][16][68];
    __shared__ float Bs[2][16][68];
    float acc[4][4] = {};

    int t = t0 + lr;
    const float* arow0 = wemb + (size_t)words[t] * 300;
    const float* arow1 = temb + (size_t)tags[t] * 100 - 300;   // indexed by k directly
    const float* brow  = B + (size_t)(n0 + lr) * 400;

    int p = 0;
    float4 av, bv;
    { int k = lk; av = (k < 300) ? *(const float4*)(arow0 + k) : *(const float4*)(arow1 + k);
      bv = *(const float4*)(brow + k); }
    for (int k0 = 0; k0 < 400; k0 += 16) {
        stage_nb(As[p], Bs[p], lk, lr, av, bv);
        int kn = k0 + 16;
        if (kn < 400) {
            int k = kn + lk;   // 300 % 4 == 0, so each float4 stays in one table
            av = (k < 300) ? *(const float4*)(arow0 + k) : *(const float4*)(arow1 + k);
            bv = *(const float4*)(brow + k);
        }
        __syncthreads();
        fma16(acc, As[p], Bs[p], tx, ty);
        p ^= 1;
    }
    float bs[4];
    #pragma unroll
    for (int j = 0; j < 4; ++j) {
        int n = n0 + tx * 4 + j;
        bs[j] = bias1[n] + bias2[n];
    }
    #pragma unroll
    for (int i = 0; i < 4; ++i) {
        int tr = t0 + ty * 4 + i;
        float4 o;
        o.x = acc[i][0] + bs[0]; o.y = acc[i][1] + bs[1];
        o.z = acc[i][2] + bs[2]; o.w = acc[i][3] + bs[3];
        *(float4*)(C + (size_t)tr * 3200 + n0 + tx * 4) = o;
    }
}

// ---------------- persistent distributed LSTM body (exact R4 logic) ----------------
#define LSTM_G 50
__device__ __forceinline__ void lstm_body(int bid,
                 const float* __restrict__ Whh,   // (2,1600,400)
                 const float* __restrict__ h0,    // (4,400)
                 const float* __restrict__ c0,    // (4,400)
                 int hc_base,
                 const float* __restrict__ xg,    // (256,3200): [t][d*1600 + gaterow]
                 u64* __restrict__ hist,          // (2,256,400)
                 u32 tag_base,
                 float (*hbuf)[416]) {
    const int T = 256;
    int d  = bid / LSTM_G;
    int wg = bid % LSTM_G;
    int a8 = wg * 8;
    int tid = threadIdx.x;
    int w = tid >> 6, lane = tid & 63;
    int c = lane & 7, r = lane >> 3;
    int gate = r >> 1, jj = r & 1;
    int gr = gate * 400 + a8 + 2 * w + jj;

    float4 wv[13];
    const float* wrow = Whh + (size_t)d * 640000 + (size_t)gr * 400;
    #pragma unroll
    for (int i = 0; i < 13; ++i) {
        int k = 4 * (c + 8 * i);
        wv[i] = (k + 3 < 400) ? *(const float4*)(wrow + k) : make_float4(0.f, 0.f, 0.f, 0.f);
    }
    if (tid < 16) { hbuf[0][400 + tid] = 0.f; hbuf[1][400 + tid] = 0.f; }

    float c_state = 0.f;
    if (lane == 0 || lane == 8)
        c_state = c0[(hc_base + d) * 400 + a8 + 2 * w + jj];

    u64* hst = hist + (size_t)d * 102400;
    bool need2 = (tid + 256 < 400);

    for (int t = 0; t < T; ++t) {
        int xt = d ? (T - 1 - t) : t;
        float xgv = xg[(size_t)xt * 3200 + d * 1600 + gr];
        float* hb = hbuf[t & 1];

        if (t == 0) {
            hb[tid] = h0[(hc_base + d) * 400 + tid];
            if (need2) hb[tid + 256] = h0[(hc_base + d) * 400 + tid + 256];
        } else {
            const u64* src = hst + (size_t)(t - 1) * 400;
            u32 want = tag_base + (u32)t;
            bool d1 = false, d2 = !need2;
            while (!(d1 && d2)) {
                u64 v1 = 0, v2 = 0;
                if (!d1) v1 = HLD(&src[tid]);
                if (!d2) v2 = HLD(&src[tid + 256]);
                if (!d1 && (u32)(v1 >> 32) == want) { hb[tid] = __uint_as_float((u32)v1); d1 = true; }
                if (!d2 && (u32)(v2 >> 32) == want) { hb[tid + 256] = __uint_as_float((u32)v2); d2 = true; }
            }
        }
        __syncthreads();

        const float4* h4 = (const float4*)hb;
        float s = 0.f;
        #pragma unroll
        for (int i = 0; i < 13; ++i) {
            float4 hv = h4[c + 8 * i];
            s += wv[i].x * hv.x + wv[i].y * hv.y + wv[i].z * hv.z + wv[i].w * hv.w;
        }
        s += __shfl_down(s, 4);
        s += __shfl_down(s, 2);
        s += __shfl_down(s, 1);

        float v = 0.f;
        if (c == 0) {
            float tot = s + xgv;
            float arg = (gate == 2) ? 2.f * tot : -tot;
            arg = fminf(fmaxf(arg, -60.f), 60.f);
            float e = __expf(arg);
            v = (gate == 2) ? (e - 1.f) * __frcp_rn(e + 1.f)
                            : __frcp_rn(1.f + e);
        }
        float fv = __shfl(v, lane + 16);
        float gv = __shfl(v, lane + 32);
        float ov = __shfl(v, lane + 48);
        if (lane == 0 || lane == 8) {
            c_state = fv * c_state + v * gv;
            float ec = __expf(fminf(fmaxf(2.f * c_state, -60.f), 60.f));
            float th = (ec - 1.f) * __frcp_rn(ec + 1.f);
            float h = ov * th;
            u64 pk = (((u64)(tag_base + t + 1)) << 32) | (u64)__float_as_uint(h);
            __hip_atomic_store(&hst[(size_t)t * 400 + a8 + 2 * w + jj], pk,
                               __ATOMIC_RELAXED, __HIP_MEMORY_SCOPE_AGENT);
        }
    }
}

// shared-memory union: GEMM tiles and LSTM hbuf never coexist in one block
union SmemU {
    struct { float As[2][16][68]; float Bs[2][16][68]; } g;
    float hbuf[2][416];
};

// ---------------- fused dispatch 2: layer-0 LSTM + layer-1 xg GEMM ----------------
// blocks 0..99: LSTM layer 0.  blocks 100..299: xg1[t][n] = hV0[t] @ Wih1[n] + bih1[n]+bhh1[n]
// (K=800, N=3200). Per-segment block gate + pipelined K-loop.
__global__ __launch_bounds__(256)
void lstm0_fused(const float* __restrict__ Whh, const float* __restrict__ h0,
                 const float* __restrict__ c0, const float* __restrict__ xg0,
                 u64* __restrict__ hist,
                 const float* __restrict__ Wih1, const float* __restrict__ bih1,
                 const float* __restrict__ bhh1, float* __restrict__ xg1) {
    __shared__ SmemU sm;
    int bid = blockIdx.x;
    if (bid < 2 * LSTM_G) {
        lstm_body(bid, Whh, h0, c0, 0, xg0, hist, 0u, sm.hbuf);
        return;
    }
    int g = bid - 2 * LSTM_G;
    int t0 = (g & 3) * 64;
    int n0 = (g >> 2) * 64;
    int tid = threadIdx.x;
    int tx = tid & 15, ty = tid >> 4;
    int lr = tid >> 2, lk = (tid & 3) * 4;
    float acc[4][4] = {};
    int t = t0 + lr;
    const float* brow = Wih1 + (size_t)(n0 + lr) * 800;

    // fwd half (k<400) ready at step t0+63; bwd half at step 255-t0 -> early half first
    int first = (t0 >= 128) ? 400 : 0;
    int pb = 0;
    for (int seg = 0; seg < 2; ++seg) {
        int kb = first ^ (seg ? 400 : 0);
        if (kb == 0) {      // fwd rows t0..t0+63: last produced at fwd step t0+63
            const u64* gw = hist + (size_t)(t0 + 63) * 400;
            gate_wait(gw, gw + 399, (u32)(t0 + 64), (u32)(t0 + 64));
        } else {            // bwd slots 255-t, max slot = 255-t0 (for row t0)
            const u64* gw = hist + 102400 + (size_t)(255 - t0) * 400;
            gate_wait(gw, gw + 399, (u32)(256 - t0), (u32)(256 - t0));
        }
        gemm_seg(sm.g.As, sm.g.Bs, acc, hist, t, t, 0u, brow, kb, 400, lk, lr, tx, ty, pb);
    }
    float bs[4];
    #pragma unroll
    for (int j = 0; j < 4; ++j) {
        int n = n0 + tx * 4 + j;
        bs[j] = bih1[n] + bhh1[n];
    }
    #pragma unroll
    for (int i = 0; i < 4; ++i) {
        int tr = t0 + ty * 4 + i;
        float4 o;
        o.x = acc[i][0] + bs[0]; o.y = acc[i][1] + bs[1];
        o.z = acc[i][2] + bs[2]; o.w = acc[i][3] + bs[3];
        *(float4*)(xg1 + (size_t)tr * 3200 + n0 + tx * 4) = o;
    }
}

// ---------------- fused dispatch 3: layer-1 LSTM + PQ/U GEMMs ----------------
// blocks 0..99: LSTM layer 1 (tags 257..512).
// blocks 100..199: U tiles (K=1600; cols 800.. gather hV1[head(t)]) -> dispatched before PQ.
// blocks 200..399: PQ tiles (K=800).  All segments gated; K-loops pipelined.
__global__ __launch_bounds__(256)
void lstm1_fused(const float* __restrict__ Whh, const float* __restrict__ h0,
                 const float* __restrict__ c0, const float* __restrict__ xg1,
                 u64* __restrict__ hist, const int* __restrict__ arcs,
                 const float* __restrict__ Wa1, const float* __restrict__ ba1,
                 const float* __restrict__ Wl1, const float* __restrict__ bl1,
                 float* __restrict__ PQ, float* __restrict__ U) {
    __shared__ SmemU sm;
    int bid = blockIdx.x;
    if (bid < 2 * LSTM_G) {
        lstm_body(bid, Whh, h0, c0, 2, xg1, hist, 256u, sm.hbuf);
        return;
    }
    int g = bid - 2 * LSTM_G;
    int t0 = (g & 3) * 64;
    int by = g >> 2;                    // 0..74: by<25 -> U tile, else PQ tile
    int tid = threadIdx.x;
    int tx = tid & 15, ty = tid >> 4;
    int lr = tid >> 2, lk = (tid & 3) * 4;
    float acc[4][4] = {};
    int t = t0 + lr;
    int first = (t0 >= 128) ? 400 : 0;  // early-available half of hV[t] first
    int pb = 0;

    if (by < 25) {
        // ---- U path ----
        int n0 = by * 64;
        int h = arcs[1 + t];
        int tind = min(max(h - 1, 0), 255);
        const float* brow = Wl1 + (size_t)(n0 + lr) * 1600;
        for (int seg = 0; seg < 3; ++seg) {
            int kb   = (seg < 2) ? (first ^ (seg ? 400 : 0)) : 800;
            int klen = (seg < 2) ? 400 : 800;
            if (seg < 2) {
                if (kb == 0) {
                    const u64* gw = hist + (size_t)(t0 + 63) * 400;
                    gate_wait(gw, gw + 399, (u32)(t0 + 320), (u32)(t0 + 320));
                } else {
                    const u64* gw = hist + 102400 + (size_t)(255 - t0) * 400;
                    gate_wait(gw, gw + 399, (u32)(512 - t0), (u32)(512 - t0));
                }
            } else {        // head gather: arbitrary rows -> need both directions complete
                const u64* gf = hist + (size_t)255 * 400;
                const u64* gb = hist + 102400 + (size_t)255 * 400;
                gate_wait(gf, gb, 512u, 512u);
            }
            gemm_seg(sm.g.As, sm.g.Bs, acc, hist, t, tind, 256u, brow, kb, klen, lk, lr, tx, ty, pb);
        }
        float bs[4];
        #pragma unroll
        for (int j = 0; j < 4; ++j) bs[j] = bl1[n0 + tx * 4 + j];
        #pragma unroll
        for (int i = 0; i < 4; ++i) {
            int tr = t0 + ty * 4 + i;
            float4 o;
            o.x = fast_tanh(acc[i][0] + bs[0]); o.y = fast_tanh(acc[i][1] + bs[1]);
            o.z = fast_tanh(acc[i][2] + bs[2]); o.w = fast_tanh(acc[i][3] + bs[3]);
            *(float4*)(U + (size_t)tr * 1600 + n0 + tx * 4) = o;
        }
    } else {
        // ---- PQ path ----
        int n0 = (by - 25) * 64;
        int nn = n0 + lr;
        const float* brow = (nn < 1600) ? Wa1 + (size_t)nn * 1600
                                        : Wa1 + (size_t)(nn - 1600) * 1600 + 800;
        for (int seg = 0; seg < 2; ++seg) {
            int kb = first ^ (seg ? 400 : 0);
            if (kb == 0) {
                const u64* gw = hist + (size_t)(t0 + 63) * 400;
                gate_wait(gw, gw + 399, (u32)(t0 + 320), (u32)(t0 + 320));
            } else {
                const u64* gw = hist + 102400 + (size_t)(255 - t0) * 400;
                gate_wait(gw, gw + 399, (u32)(512 - t0), (u32)(512 - t0));
            }
            gemm_seg(sm.g.As, sm.g.Bs, acc, hist, t, t, 256u, brow, kb, 400, lk, lr, tx, ty, pb);
        }
        float bs[4];
        #pragma unroll
        for (int j = 0; j < 4; ++j) {
            int n = n0 + tx * 4 + j;
            bs[j] = (n < 1600) ? ba1[n] : 0.f;
        }
        #pragma unroll
        for (int i = 0; i < 4; ++i) {
            int tr = t0 + ty * 4 + i;
            float4 o;
            o.x = acc[i][0] + bs[0]; o.y = acc[i][1] + bs[1];
            o.z = acc[i][2] + bs[2]; o.w = acc[i][3] + bs[3];
            *(float4*)(PQ + (size_t)tr * 3200 + n0 + tx * 4) = o;
        }
    }
}

// ---------------- arc pairwise scorer (+ borders, folded in) ----------------
__global__ __launch_bounds__(256)
void arc_kernel(const float* __restrict__ PQ,
                const float* __restrict__ Wa2, const float* __restrict__ ba2,
                float* __restrict__ out) {
    int i0 = blockIdx.x * 16, j0 = blockIdx.y * 16;
    int tid = threadIdx.x;
    int ii = tid >> 4, jj = tid & 15;
    __shared__ float Pt[16][65], Qt[16][65];
    __shared__ float W2f[1600];

    if (i0 == 0 && j0 == 0) {   // borders: row 0 (with [0,0]=1) and col 0
        if (tid < 257) out[tid] = (tid == 0) ? 1.0f : 0.0f;
        out[(size_t)(tid + 1) * 257] = 0.0f;
        if (tid == 0) out[0] = 1.0f;
    }
    for (int m = tid; m < 1600; m += 256) W2f[m] = Wa2[m];
    __syncthreads();

    float acc = 0.f;
    int mm = tid & 63, r4 = tid >> 6;
    for (int m0 = 0; m0 < 1600; m0 += 64) {
        #pragma unroll
        for (int rr = r4; rr < 16; rr += 4) {
            Pt[rr][mm] = PQ[(size_t)(i0 + rr) * 3200 + m0 + mm];
            Qt[rr][mm] = PQ[(size_t)(j0 + rr) * 3200 + 1600 + m0 + mm];
        }
        __syncthreads();
        #pragma unroll 8
        for (int m = 0; m < 64; ++m) {
            float s = Pt[ii][m] + Qt[jj][m];
            acc += W2f[m0 + m] * fast_tanh(s);
        }
        __syncthreads();
    }
    float raw = acc + ba2[0];
    int gi = i0 + ii, gj = j0 + jj;
    if (gi == gj) raw = 0.f;
    out[(size_t)(gi + 1) * 257 + (gj + 1)] = raw;
}

// ---------------- label output ----------------
__global__ __launch_bounds__(256)
void label_out_kernel(const float* __restrict__ U, const float* __restrict__ Wl2,
                      const float* __restrict__ bl2, const int* __restrict__ arcs,
                      float* __restrict__ out) {
    int t = blockIdx.x;
    __shared__ float u_l[1600];
    __shared__ float part[4][64];
    for (int m = threadIdx.x; m < 1600; m += 256) u_l[m] = U[(size_t)t * 1600 + m];
    __syncthreads();
    int tid = threadIdx.x;
    int n = tid & 63, p = tid >> 6;
    float acc = 0.f;
    if (n < 40) {
        const float4* wr4 = (const float4*)(Wl2 + (size_t)n * 1600 + p * 400);
        const float*  ub  = u_l + p * 400;
        for (int m = 0; m < 100; ++m) {
            float4 w = wr4[m];
            acc += ub[4*m] * w.x + ub[4*m+1] * w.y + ub[4*m+2] * w.z + ub[4*m+3] * w.w;
        }
    }
    part[p][n] = acc;
    __syncthreads();
    if (tid < 40) {
        float v = part[0][tid] + part[1][tid] + part[2][tid] + part[3][tid] + bl2[tid];
        if (arcs[1 + t] == 0) v = 0.f;
        out[(size_t)t * 40 + tid] = v;
    }
}

// ---------------- launch ----------------
extern "C" void kernel_launch(void* const* d_in, const int* in_sizes, int n_in,
                              void* d_out, int out_size, void* d_ws, size_t ws_size,
                              hipStream_t stream) {
    const int*   words = (const int*)d_in[0];
    const int*   tags  = (const int*)d_in[1];
    const int*   arcs  = (const int*)d_in[2];
    const float* h0    = (const float*)d_in[3];
    const float* c0    = (const float*)d_in[4];
    const float* wemb  = (const float*)d_in[5];
    const float* temb  = (const float*)d_in[6];
    const float* Wih0  = (const float*)d_in[7];
    const float* Whh0  = (const float*)d_in[8];
    const float* bih0  = (const float*)d_in[9];
    const float* bhh0  = (const float*)d_in[10];
    const float* Wih1  = (const float*)d_in[11];
    const float* Whh1  = (const float*)d_in[12];
    const float* bih1  = (const float*)d_in[13];
    const float* bhh1  = (const float*)d_in[14];
    const float* Wa1   = (const float*)d_in[15];
    const float* ba1   = (const float*)d_in[16];
    const float* Wa2   = (const float*)d_in[17];
    const float* ba2   = (const float*)d_in[18];
    const float* Wl1   = (const float*)d_in[19];
    const float* bl1   = (const float*)d_in[20];
    const float* Wl2   = (const float*)d_in[21];
    const float* bl2   = (const float*)d_in[22];
    float* out = (float*)d_out;

    char* ws = (char*)d_ws;
    float* xg0  = (float*)(ws + OF_XG);   // layer-0 gates; region reused for PQ afterwards
    u64*   hist = (u64*)  (ws + OF_H);
    float* xg1  = (float*)(ws + OF_PQ);   // layer-1 gates live where PQ used to
    float* PQ   = (float*)(ws + OF_XG);   // PQ overwrites dead xg0
    float* U    = (float*)(ws + OF_U);

    gemm_embed_kernel<<<dim3(4, 50), 256, 0, stream>>>(words, tags, wemb, temb, Wih0, bih0, bhh0, xg0);
    lstm0_fused<<<300, 256, 0, stream>>>(Whh0, h0, c0, xg0, hist, Wih1, bih1, bhh1, xg1);
    lstm1_fused<<<400, 256, 0, stream>>>(Whh1, h0, c0, xg1, hist, arcs, Wa1, ba1, Wl1, bl1, PQ, U);
    arc_kernel<<<dim3(16, 16), 256, 0, stream>>>(PQ, Wa2, ba2, out);
    label_out_kernel<<<256, 256, 0, stream>>>(U, Wl2, bl2, arcs, out + 66049);
}

// Round 6
// 1137.349 us; speedup vs baseline: 1.1122x; 1.0014x over previous
//
#include <hip/hip_runtime.h>

typedef unsigned int   u32;
typedef unsigned long long u64;

// ---------------- helpers ----------------
__device__ __forceinline__ float fast_tanh(float x) {
    x = fminf(fmaxf(x, -15.f), 15.f);
    float e = __expf(2.f * x);
    return __fdividef(e - 1.f, e + 1.f);
}

#define HLD(p) __hip_atomic_load((p), __ATOMIC_RELAXED, __HIP_MEMORY_SCOPE_AGENT)

// ---------------- workspace layout (bytes, all fp32) ----------------
// OF_XG: xg0 (layer-0 gates), later reused for PQ.  OF_PQ: xg1 (layer-1 gates).
// hist: 2x256x400 u64 tag-versioned (reused by both layers, disjoint tag ranges).
#define OF_XG   ((size_t)0)
#define OF_H    (OF_XG + 3276800)
#define OF_PQ   (OF_H  + 1638400)
#define OF_U    (OF_PQ + 3276800)

// ---- pipelined tag-verified hist read: issue early, verify at consume ----
// layer tag ranges: layer0 base=0 -> tags 1..256; layer1 base=256 -> tags 257..512.
struct H4 { u64 v0, v1, v2, v3; const u64* p; u32 want; };

__device__ __forceinline__ H4 h4_issue(const u64* __restrict__ hist, int t, int k, u32 base) {
    H4 h;
    if (k < 400) { h.p = hist + (size_t)t * 400 + k;                          h.want = base + (u32)t + 1u; }
    else         { h.p = hist + 102400 + (size_t)(255 - t) * 400 + (k - 400); h.want = base + (u32)(255 - t) + 1u; }
    h.v0 = HLD(h.p + 0); h.v1 = HLD(h.p + 1); h.v2 = HLD(h.p + 2); h.v3 = HLD(h.p + 3);
    return h;
}

__device__ __forceinline__ float4 h4_fin(H4 h) {
    while ((u32)(h.v0 >> 32) != h.want || (u32)(h.v1 >> 32) != h.want ||
           (u32)(h.v2 >> 32) != h.want || (u32)(h.v3 >> 32) != h.want) {
        __builtin_amdgcn_s_sleep(4);    // rare: post-gate miss only
        h.v0 = HLD(h.p + 0); h.v1 = HLD(h.p + 1); h.v2 = HLD(h.p + 2); h.v3 = HLD(h.p + 3);
    }
    return make_float4(__uint_as_float((u32)h.v0), __uint_as_float((u32)h.v1),
                       __uint_as_float((u32)h.v2), __uint_as_float((u32)h.v3));
}

// ---- block-level gate on hist tags: ONE thread polls two sample words ----
__device__ __forceinline__ void gate_wait(const u64* __restrict__ w0, const u64* __restrict__ w1,
                                          u32 want0, u32 want1) {
    if (threadIdx.x == 0) {
        for (;;) {
            u32 g0 = (u32)(HLD(w0) >> 32);
            u32 g1 = (u32)(HLD(w1) >> 32);
            if (g0 == want0 && g1 == want1) break;
            __builtin_amdgcn_s_sleep(16);
        }
    }
    __syncthreads();
}

// ---- block-level gate on a completion counter (acquire on exit for cache inv) ----
__device__ __forceinline__ void gate_cnt(const u32* __restrict__ c, u32 target) {
    if (threadIdx.x == 0) {
        while (__hip_atomic_load(c, __ATOMIC_RELAXED, __HIP_MEMORY_SCOPE_AGENT) < target)
            __builtin_amdgcn_s_sleep(16);
        (void)__hip_atomic_load(c, __ATOMIC_ACQUIRE, __HIP_MEMORY_SCOPE_AGENT);
    }
    __syncthreads();
}

// ---- GEMM micro-kernel pieces (64x64 tile, 16-deep K step, double-buffered LDS) ----
__device__ __forceinline__ void stage_nb(float (*As)[68], float (*Bs)[68],
                                         int lk, int lr, float4 av, float4 bv) {
    As[lk + 0][lr] = av.x; As[lk + 1][lr] = av.y; As[lk + 2][lr] = av.z; As[lk + 3][lr] = av.w;
    Bs[lk + 0][lr] = bv.x; Bs[lk + 1][lr] = bv.y; Bs[lk + 2][lr] = bv.z; Bs[lk + 3][lr] = bv.w;
}

__device__ __forceinline__ void fma16(float acc[4][4], const float (*As)[68], const float (*Bs)[68],
                                      int tx, int ty) {
    #pragma unroll
    for (int kk = 0; kk < 16; ++kk) {
        float4 a4 = *(const float4*)&As[kk][ty * 4];
        float4 b4 = *(const float4*)&Bs[kk][tx * 4];
        acc[0][0] += a4.x * b4.x; acc[0][1] += a4.x * b4.y; acc[0][2] += a4.x * b4.z; acc[0][3] += a4.x * b4.w;
        acc[1][0] += a4.y * b4.x; acc[1][1] += a4.y * b4.y; acc[1][2] += a4.y * b4.z; acc[1][3] += a4.y * b4.w;
        acc[2][0] += a4.z * b4.x; acc[2][1] += a4.z * b4.y; acc[2][2] += a4.z * b4.z; acc[2][3] += a4.z * b4.w;
        acc[3][0] += a4.w * b4.x; acc[3][1] += a4.w * b4.y; acc[3][2] += a4.w * b4.z; acc[3][3] += a4.w * b4.w;
    }
}

// one K-segment of a hist-consuming GEMM, software-pipelined one step deep.
__device__ __forceinline__ void gemm_seg(float (*AsB)[16][68], float (*BsB)[16][68],
        float acc[4][4], const u64* __restrict__ hist, int t, int tind, u32 base,
        const float* __restrict__ brow, int kb, int klen,
        int lk, int lr, int tx, int ty, int& pb)
{
    int ka = kb + lk;
    H4 h = h4_issue(hist, ka < 800 ? t : tind, ka < 800 ? ka : ka - 800, base);
    float4 bv = *(const float4*)(brow + ka);
    for (int k0 = kb; k0 < kb + klen; k0 += 16) {
        float4 av = h4_fin(h);
        stage_nb(AsB[pb], BsB[pb], lk, lr, av, bv);
        int kn = k0 + 16;
        if (kn < kb + klen) {
            int k2 = kn + lk;
            h  = h4_issue(hist, k2 < 800 ? t : tind, k2 < 800 ? k2 : k2 - 800, base);
            bv = *(const float4*)(brow + k2);
        }
        __syncthreads();                 // single barrier per K-step (double buffer)
        fma16(acc, AsB[pb], BsB[pb], tx, ty);
        pb ^= 1;
    }
}

// ---------------- GEMM with A gathered from embeddings (layer-0 xg) ----------------
// also zeroes the 4 xg1-completion counters (block (0,0)) for the mega dispatch.
__global__ __launch_bounds__(256)
void gemm_embed_kernel(const int* __restrict__ words, const int* __restrict__ tags,
                       const float* __restrict__ wemb, const float* __restrict__ temb,
                       const float* __restrict__ B,
                       const float* __restrict__ bias1, const float* __restrict__ bias2,
                       float* __restrict__ C, u32* __restrict__ cnt) {
    int t0 = blockIdx.x * 64;
    int n0 = blockIdx.y * 64;
    int tid = threadIdx.x;
    if (blockIdx.x == 0 && blockIdx.y == 0 && tid < 4) cnt[tid] = 0u;
    int tx = tid & 15, ty = tid >> 4;
    int lr = tid >> 2, lk = (tid & 3) * 4;
    __shared__ float As[2][16][68];
    __shared__ float Bs[2][16][68];
    float acc[4][4] = {};

    int t = t0 + lr;
    const float* arow0 = wemb + (size_t)words[t] * 300;
    const float* arow1 = temb + (size_t)tags[t] * 100 - 300;   // indexed by k directly
    const float* brow  = B + (size_t)(n0 + lr) * 400;

    int p = 0;
    float4 av, bv;
    { int k = lk; av = (k < 300) ? *(const float4*)(arow0 + k) : *(const float4*)(arow1 + k);
      bv = *(const float4*)(brow + k); }
    for (int k0 = 0; k0 < 400; k0 += 16) {
        stage_nb(As[p], Bs[p], lk, lr, av, bv);
        int kn = k0 + 16;
        if (kn < 400) {
            int k = kn + lk;   // 300 % 4 == 0, so each float4 stays in one table
            av = (k < 300) ? *(const float4*)(arow0 + k) : *(const float4*)(arow1 + k);
            bv = *(const float4*)(brow + k);
        }
        __syncthreads();
        fma16(acc, As[p], Bs[p], tx, ty);
        p ^= 1;
    }
    float bs[4];
    #pragma unroll
    for (int j = 0; j < 4; ++j) {
        int n = n0 + tx * 4 + j;
        bs[j] = bias1[n] + bias2[n];
    }
    #pragma unroll
    for (int i = 0; i < 4; ++i) {
        int tr = t0 + ty * 4 + i;
        float4 o;
        o.x = acc[i][0] + bs[0]; o.y = acc[i][1] + bs[1];
        o.z = acc[i][2] + bs[2]; o.w = acc[i][3] + bs[3];
        *(float4*)(C + (size_t)tr * 3200 + n0 + tx * 4) = o;
    }
}

// ---------------- persistent distributed LSTM body (exact R4 logic) ----------------
#define LSTM_G 50
__device__ __forceinline__ void lstm_body(int bid,
                 const float* __restrict__ Whh,   // (2,1600,400)
                 const float* __restrict__ h0,    // (4,400)
                 const float* __restrict__ c0,    // (4,400)
                 int hc_base,
                 const float* __restrict__ xg,    // (256,3200): [t][d*1600 + gaterow]
                 u64* __restrict__ hist,          // (2,256,400)
                 u32 tag_base,
                 float (*hbuf)[416],
                 const u32* __restrict__ cnt) {   // non-null: gate on all xg1 tiles first
    const int T = 256;
    int d  = bid / LSTM_G;
    int wg = bid % LSTM_G;
    int a8 = wg * 8;
    int tid = threadIdx.x;
    int w = tid >> 6, lane = tid & 63;
    int c = lane & 7, r = lane >> 3;
    int gate = r >> 1, jj = r & 1;
    int gr = gate * 400 + a8 + 2 * w + jj;

    float4 wv[13];
    const float* wrow = Whh + (size_t)d * 640000 + (size_t)gr * 400;
    #pragma unroll
    for (int i = 0; i < 13; ++i) {
        int k = 4 * (c + 8 * i);
        wv[i] = (k + 3 < 400) ? *(const float4*)(wrow + k) : make_float4(0.f, 0.f, 0.f, 0.f);
    }
    if (tid < 16) { hbuf[0][400 + tid] = 0.f; hbuf[1][400 + tid] = 0.f; }

    float c_state = 0.f;
    if (lane == 0 || lane == 8)
        c_state = c0[(hc_base + d) * 400 + a8 + 2 * w + jj];

    // layer-1: wait until ALL xg1 GEMM blocks finished (they also finished READING
    // layer-0 hist, so overwriting hist with layer-1 tags below is safe).
    if (cnt) { gate_cnt(&cnt[0], 50); gate_cnt(&cnt[1], 50); gate_cnt(&cnt[2], 50); gate_cnt(&cnt[3], 50); }

    u64* hst = hist + (size_t)d * 102400;
    bool need2 = (tid + 256 < 400);

    for (int t = 0; t < T; ++t) {
        int xt = d ? (T - 1 - t) : t;
        float xgv = xg[(size_t)xt * 3200 + d * 1600 + gr];
        float* hb = hbuf[t & 1];

        if (t == 0) {
            hb[tid] = h0[(hc_base + d) * 400 + tid];
            if (need2) hb[tid + 256] = h0[(hc_base + d) * 400 + tid + 256];
        } else {
            const u64* src = hst + (size_t)(t - 1) * 400;
            u32 want = tag_base + (u32)t;
            bool d1 = false, d2 = !need2;
            while (!(d1 && d2)) {
                u64 v1 = 0, v2 = 0;
                if (!d1) v1 = HLD(&src[tid]);
                if (!d2) v2 = HLD(&src[tid + 256]);
                if (!d1 && (u32)(v1 >> 32) == want) { hb[tid] = __uint_as_float((u32)v1); d1 = true; }
                if (!d2 && (u32)(v2 >> 32) == want) { hb[tid + 256] = __uint_as_float((u32)v2); d2 = true; }
            }
        }
        __syncthreads();

        const float4* h4 = (const float4*)hb;
        float s = 0.f;
        #pragma unroll
        for (int i = 0; i < 13; ++i) {
            float4 hv = h4[c + 8 * i];
            s += wv[i].x * hv.x + wv[i].y * hv.y + wv[i].z * hv.z + wv[i].w * hv.w;
        }
        s += __shfl_down(s, 4);
        s += __shfl_down(s, 2);
        s += __shfl_down(s, 1);

        float v = 0.f;
        if (c == 0) {
            float tot = s + xgv;
            float arg = (gate == 2) ? 2.f * tot : -tot;
            arg = fminf(fmaxf(arg, -60.f), 60.f);
            float e = __expf(arg);
            v = (gate == 2) ? (e - 1.f) * __frcp_rn(e + 1.f)
                            : __frcp_rn(1.f + e);
        }
        float fv = __shfl(v, lane + 16);
        float gv = __shfl(v, lane + 32);
        float ov = __shfl(v, lane + 48);
        if (lane == 0 || lane == 8) {
            c_state = fv * c_state + v * gv;
            float ec = __expf(fminf(fmaxf(2.f * c_state, -60.f), 60.f));
            float th = (ec - 1.f) * __frcp_rn(ec + 1.f);
            float h = ov * th;
            u64 pk = (((u64)(tag_base + t + 1)) << 32) | (u64)__float_as_uint(h);
            __hip_atomic_store(&hst[(size_t)t * 400 + a8 + 2 * w + jj], pk,
                               __ATOMIC_RELAXED, __HIP_MEMORY_SCOPE_AGENT);
        }
    }
}

// shared-memory union: GEMM tiles and LSTM hbuf never coexist in one block
union SmemU {
    struct { float As[2][16][68]; float Bs[2][16][68]; } g;
    float hbuf[2][416];
};

// ---------------- MEGA dispatch: both LSTM layers + xg1 GEMM + PQ/U GEMMs ----------------
// blocks   0.. 99: LSTM layer 0 (tags 1..256)
// blocks 100..299: xg1 GEMM (gated on layer-0 hist tags; increments cnt[t-tile] when done)
// blocks 300..399: LSTM layer 1 (gated on cnt[0..3]==50; tags 257..512)
// blocks 400..499: U tiles   (pre-gated on cnt, then layer-1 hist tags)
// blocks 500..699: PQ tiles  (pre-gated on cnt, then layer-1 hist tags)
// Dependency order == block order; 700 blocks (2800 waves, ~12MB LDS) are fully
// co-resident so no dispatch-order assumption is needed for forward progress.
__global__ __launch_bounds__(256)
void mega_kernel(const float* __restrict__ Whh0, const float* __restrict__ Whh1,
                 const float* __restrict__ h0, const float* __restrict__ c0,
                 const float* __restrict__ xg0, float* __restrict__ xg1,
                 u64* __restrict__ hist, const int* __restrict__ arcs,
                 const float* __restrict__ Wih1, const float* __restrict__ bih1,
                 const float* __restrict__ bhh1,
                 const float* __restrict__ Wa1, const float* __restrict__ ba1,
                 const float* __restrict__ Wl1, const float* __restrict__ bl1,
                 float* __restrict__ PQ, float* __restrict__ U, u32* __restrict__ cnt) {
    __shared__ SmemU sm;
    int bid = blockIdx.x;
    int tid = threadIdx.x;

    if (bid < 100) {            // ---- LSTM layer 0 ----
        lstm_body(bid, Whh0, h0, c0, 0, xg0, hist, 0u, sm.hbuf, nullptr);
        return;
    }
    if (bid < 300) {            // ---- xg1 GEMM ----
        int g = bid - 100;
        int t0 = (g & 3) * 64;
        int n0 = (g >> 2) * 64;
        int tx = tid & 15, ty = tid >> 4;
        int lr = tid >> 2, lk = (tid & 3) * 4;
        float acc[4][4] = {};
        int t = t0 + lr;
        const float* brow = Wih1 + (size_t)(n0 + lr) * 800;

        int first = (t0 >= 128) ? 400 : 0;
        int pb = 0;
        for (int seg = 0; seg < 2; ++seg) {
            int kb = first ^ (seg ? 400 : 0);
            if (kb == 0) {      // fwd rows t0..t0+63: last produced at fwd step t0+63
                const u64* gw = hist + (size_t)(t0 + 63) * 400;
                gate_wait(gw, gw + 399, (u32)(t0 + 64), (u32)(t0 + 64));
            } else {            // bwd slots 255-t, max slot = 255-t0 (for row t0)
                const u64* gw = hist + 102400 + (size_t)(255 - t0) * 400;
                gate_wait(gw, gw + 399, (u32)(256 - t0), (u32)(256 - t0));
            }
            gemm_seg(sm.g.As, sm.g.Bs, acc, hist, t, t, 0u, brow, kb, 400, lk, lr, tx, ty, pb);
        }
        float bs[4];
        #pragma unroll
        for (int j = 0; j < 4; ++j) {
            int n = n0 + tx * 4 + j;
            bs[j] = bih1[n] + bhh1[n];
        }
        #pragma unroll
        for (int i = 0; i < 4; ++i) {
            int tr = t0 + ty * 4 + i;
            float4 o;
            o.x = acc[i][0] + bs[0]; o.y = acc[i][1] + bs[1];
            o.z = acc[i][2] + bs[2]; o.w = acc[i][3] + bs[3];
            *(float4*)(xg1 + (size_t)tr * 3200 + n0 + tx * 4) = o;
        }
        __syncthreads();        // all tile writes issued & drained (vmcnt at barrier)
        if (tid == 0)           // release: flush XCD L2, then signal completion
            __hip_atomic_fetch_add(&cnt[t0 >> 6], 1u, __ATOMIC_RELEASE, __HIP_MEMORY_SCOPE_AGENT);
        return;
    }
    if (bid < 400) {            // ---- LSTM layer 1 ----
        lstm_body(bid - 300, Whh1, h0, c0, 2, xg1, hist, 256u, sm.hbuf, cnt);
        return;
    }

    // ---- U / PQ tiles: first ensure all xg1 GEMMs done (=> hist fully holds this-launch
    // layer-0 tags => layer-1 tag matches below cannot be stale from a previous replay).
    gate_cnt(&cnt[0], 50); gate_cnt(&cnt[1], 50); gate_cnt(&cnt[2], 50); gate_cnt(&cnt[3], 50);

    int tx = tid & 15, ty = tid >> 4;
    int lr = tid >> 2, lk = (tid & 3) * 4;
    float acc[4][4] = {};
    int pb = 0;

    if (bid < 500) {            // ---- U path ----
        int g = bid - 400;
        int t0 = (g & 3) * 64;
        int n0 = (g >> 2) * 64;
        int t = t0 + lr;
        int first = (t0 >= 128) ? 400 : 0;
        int h = arcs[1 + t];
        int tind = min(max(h - 1, 0), 255);
        const float* brow = Wl1 + (size_t)(n0 + lr) * 1600;
        for (int seg = 0; seg < 3; ++seg) {
            int kb   = (seg < 2) ? (first ^ (seg ? 400 : 0)) : 800;
            int klen = (seg < 2) ? 400 : 800;
            if (seg < 2) {
                if (kb == 0) {
                    const u64* gw = hist + (size_t)(t0 + 63) * 400;
                    gate_wait(gw, gw + 399, (u32)(t0 + 320), (u32)(t0 + 320));
                } else {
                    const u64* gw = hist + 102400 + (size_t)(255 - t0) * 400;
                    gate_wait(gw, gw + 399, (u32)(512 - t0), (u32)(512 - t0));
                }
            } else {            // head gather: arbitrary rows -> need both directions complete
                const u64* gf = hist + (size_t)255 * 400;
                const u64* gb = hist + 102400 + (size_t)255 * 400;
                gate_wait(gf, gb, 512u, 512u);
            }
            gemm_seg(sm.g.As, sm.g.Bs, acc, hist, t, tind, 256u, brow, kb, klen, lk, lr, tx, ty, pb);
        }
        float bs[4];
        #pragma unroll
        for (int j = 0; j < 4; ++j) bs[j] = bl1[n0 + tx * 4 + j];
        #pragma unroll
        for (int i = 0; i < 4; ++i) {
            int tr = t0 + ty * 4 + i;
            float4 o;
            o.x = fast_tanh(acc[i][0] + bs[0]); o.y = fast_tanh(acc[i][1] + bs[1]);
            o.z = fast_tanh(acc[i][2] + bs[2]); o.w = fast_tanh(acc[i][3] + bs[3]);
            *(float4*)(U + (size_t)tr * 1600 + n0 + tx * 4) = o;
        }
    } else {                    // ---- PQ path ----
        int g = bid - 500;
        int t0 = (g & 3) * 64;
        int n0 = (g >> 2) * 64;
        int t = t0 + lr;
        int first = (t0 >= 128) ? 400 : 0;
        int nn = n0 + lr;
        const float* brow = (nn < 1600) ? Wa1 + (size_t)nn * 1600
                                        : Wa1 + (size_t)(nn - 1600) * 1600 + 800;
        for (int seg = 0; seg < 2; ++seg) {
            int kb = first ^ (seg ? 400 : 0);
            if (kb == 0) {
                const u64* gw = hist + (size_t)(t0 + 63) * 400;
                gate_wait(gw, gw + 399, (u32)(t0 + 320), (u32)(t0 + 320));
            } else {
                const u64* gw = hist + 102400 + (size_t)(255 - t0) * 400;
                gate_wait(gw, gw + 399, (u32)(512 - t0), (u32)(512 - t0));
            }
            gemm_seg(sm.g.As, sm.g.Bs, acc, hist, t, t, 256u, brow, kb, 400, lk, lr, tx, ty, pb);
        }
        float bs[4];
        #pragma unroll
        for (int j = 0; j < 4; ++j) {
            int n = n0 + tx * 4 + j;
            bs[j] = (n < 1600) ? ba1[n] : 0.f;
        }
        #pragma unroll
        for (int i = 0; i < 4; ++i) {
            int tr = t0 + ty * 4 + i;
            float4 o;
            o.x = acc[i][0] + bs[0]; o.y = acc[i][1] + bs[1];
            o.z = acc[i][2] + bs[2]; o.w = acc[i][3] + bs[3];
            *(float4*)(PQ + (size_t)tr * 3200 + n0 + tx * 4) = o;
        }
    }
}

// ---------------- arc pairwise scorer: 8x8 tiles, 1024 blocks (4x occupancy) ----------------
// raw[i,j] = ba2 + sum_m Wa2[m]*tanh(P[i][m]+Q[j][m]); 4-thread m-split per output.
__global__ __launch_bounds__(256)
void arc_kernel(const float* __restrict__ PQ,
                const float* __restrict__ Wa2, const float* __restrict__ ba2,
                float* __restrict__ out) {
    int i0 = blockIdx.x * 8, j0 = blockIdx.y * 8;
    int tid = threadIdx.x;
    __shared__ float Pt[8][66], Qt[8][66];
    __shared__ float W2f[1600];
    __shared__ float part[4][64];

    if (blockIdx.x == 0 && blockIdx.y == 0) {   // borders: row 0 (with [0,0]=1) and col 0
        if (tid < 257) out[tid] = (tid == 0) ? 1.0f : 0.0f;
        out[(size_t)(tid + 1) * 257] = 0.0f;
        if (tid == 0) out[0] = 1.0f;
    }
    for (int m = tid; m < 1600; m += 256) W2f[m] = Wa2[m];

    int out_i = tid & 63, ii = out_i >> 3, jj = out_i & 7, mc = tid >> 6;
    int slr = tid >> 5, slc = (tid & 31) * 2;   // stage: 8 rows x 64 cols via float2
    float acc = 0.f;
    for (int m0 = 0; m0 < 1600; m0 += 64) {
        float2 pv = *(const float2*)(PQ + (size_t)(i0 + slr) * 3200 + m0 + slc);
        float2 qv = *(const float2*)(PQ + (size_t)(j0 + slr) * 3200 + 1600 + m0 + slc);
        __syncthreads();
        Pt[slr][slc] = pv.x; Pt[slr][slc + 1] = pv.y;
        Qt[slr][slc] = qv.x; Qt[slr][slc + 1] = qv.y;
        __syncthreads();
        #pragma unroll
        for (int mm = 0; mm < 16; ++mm) {
            int m = mc * 16 + mm;
            float s = Pt[ii][m] + Qt[jj][m];
            acc += W2f[m0 + m] * fast_tanh(s);
        }
    }
    part[mc][out_i] = acc;
    __syncthreads();
    if (tid < 64) {
        float raw = part[0][tid] + part[1][tid] + part[2][tid] + part[3][tid] + ba2[0];
        int gi = i0 + (tid >> 3), gj = j0 + (tid & 7);
        if (gi == gj) raw = 0.f;
        out[(size_t)(gi + 1) * 257 + (gj + 1)] = raw;
    }
}

// ---------------- label output ----------------
__global__ __launch_bounds__(256)
void label_out_kernel(const float* __restrict__ U, const float* __restrict__ Wl2,
                      const float* __restrict__ bl2, const int* __restrict__ arcs,
                      float* __restrict__ out) {
    int t = blockIdx.x;
    __shared__ float u_l[1600];
    __shared__ float part[4][64];
    for (int m = threadIdx.x; m < 1600; m += 256) u_l[m] = U[(size_t)t * 1600 + m];
    __syncthreads();
    int tid = threadIdx.x;
    int n = tid & 63, p = tid >> 6;
    float acc = 0.f;
    if (n < 40) {
        const float4* wr4 = (const float4*)(Wl2 + (size_t)n * 1600 + p * 400);
        const float*  ub  = u_l + p * 400;
        for (int m = 0; m < 100; ++m) {
            float4 w = wr4[m];
            acc += ub[4*m] * w.x + ub[4*m+1] * w.y + ub[4*m+2] * w.z + ub[4*m+3] * w.w;
        }
    }
    part[p][n] = acc;
    __syncthreads();
    if (tid < 40) {
        float v = part[0][tid] + part[1][tid] + part[2][tid] + part[3][tid] + bl2[tid];
        if (arcs[1 + t] == 0) v = 0.f;
        out[(size_t)t * 40 + tid] = v;
    }
}

// ---------------- launch ----------------
extern "C" void kernel_launch(void* const* d_in, const int* in_sizes, int n_in,
                              void* d_out, int out_size, void* d_ws, size_t ws_size,
                              hipStream_t stream) {
    const int*   words = (const int*)d_in[0];
    const int*   tags  = (const int*)d_in[1];
    const int*   arcs  = (const int*)d_in[2];
    const float* h0    = (const float*)d_in[3];
    const float* c0    = (const float*)d_in[4];
    const float* wemb  = (const float*)d_in[5];
    const float* temb  = (const float*)d_in[6];
    const float* Wih0  = (const float*)d_in[7];
    const float* Whh0  = (const float*)d_in[8];
    const float* bih0  = (const float*)d_in[9];
    const float* bhh0  = (const float*)d_in[10];
    const float* Wih1  = (const float*)d_in[11];
    const float* Whh1  = (const float*)d_in[12];
    const float* bih1  = (const float*)d_in[13];
    const float* bhh1  = (const float*)d_in[14];
    const float* Wa1   = (const float*)d_in[15];
    const float* ba1   = (const float*)d_in[16];
    const float* Wa2   = (const float*)d_in[17];
    const float* ba2   = (const float*)d_in[18];
    const float* Wl1   = (const float*)d_in[19];
    const float* bl1   = (const float*)d_in[20];
    const float* Wl2   = (const float*)d_in[21];
    const float* bl2   = (const float*)d_in[22];
    float* out = (float*)d_out;

    char* ws = (char*)d_ws;
    float* xg0  = (float*)(ws + OF_XG);   // layer-0 gates; region reused for PQ afterwards
    u64*   hist = (u64*)  (ws + OF_H);
    float* xg1  = (float*)(ws + OF_PQ);   // layer-1 gates live where PQ used to
    float* PQ   = (float*)(ws + OF_XG);   // PQ overwrites dead xg0
    float* U    = (float*)(ws + OF_U);
    // 4 completion counters live in score-matrix words (row 256) that arc_kernel
    // overwrites AFTER the mega dispatch -> no workspace growth, replay-safe.
    u32*   cnt  = (u32*)out + 66040;

    gemm_embed_kernel<<<dim3(4, 50), 256, 0, stream>>>(words, tags, wemb, temb, Wih0, bih0, bhh0, xg0, cnt);
    mega_kernel<<<700, 256, 0, stream>>>(Whh0, Whh1, h0, c0, xg0, xg1, hist, arcs,
                                         Wih1, bih1, bhh1, Wa1, ba1, Wl1, bl1, PQ, U, cnt);
    arc_kernel<<<dim3(32, 32), 256, 0, stream>>>(PQ, Wa2, ba2, out);
    label_out_kernel<<<256, 256, 0, stream>>>(U, Wl2, bl2, arcs, out + 66049);
}

// Round 7
// 1128.732 us; speedup vs baseline: 1.1207x; 1.0076x over previous
//
#include <hip/hip_runtime.h>

typedef unsigned int   u32;
typedef unsigned long long u64;

// ---------------- helpers ----------------
__device__ __forceinline__ float fast_tanh(float x) {
    x = fminf(fmaxf(x, -15.f), 15.f);
    float e = __expf(2.f * x);
    return __fdividef(e - 1.f, e + 1.f);
}

#define HLD(p) __hip_atomic_load((p), __ATOMIC_RELAXED, __HIP_MEMORY_SCOPE_AGENT)

// ---------------- workspace layout (bytes, all fp32) ----------------
// OF_XG: xg0 (layer-0 gates) -> later overwritten by PQ.
// OF_PQ: xg1 (layer-1 gates) -> later overwritten by ULVR (256x3200: cols<1600 UL, >=1600 VR).
//   ULVR-over-xg1 safety: a ULVR tile's global writes happen only in its epilogue, after
//   both hist gates released, which certify L1 consumed exactly those xg1 rows.
// hist: 2x256x400 u64 tag-versioned (both layers, disjoint tag ranges).
#define OF_XG   ((size_t)0)
#define OF_H    (OF_XG + 3276800)
#define OF_PQ   (OF_H  + 1638400)

// ---- pipelined tag-verified hist read: issue early, verify at consume ----
// layer tag ranges: layer0 base=0 -> tags 1..256; layer1 base=256 -> tags 257..512.
struct H4 { u64 v0, v1, v2, v3; const u64* p; u32 want; };

__device__ __forceinline__ H4 h4_issue(const u64* __restrict__ hist, int t, int k, u32 base) {
    H4 h;
    if (k < 400) { h.p = hist + (size_t)t * 400 + k;                          h.want = base + (u32)t + 1u; }
    else         { h.p = hist + 102400 + (size_t)(255 - t) * 400 + (k - 400); h.want = base + (u32)(255 - t) + 1u; }
    h.v0 = HLD(h.p + 0); h.v1 = HLD(h.p + 1); h.v2 = HLD(h.p + 2); h.v3 = HLD(h.p + 3);
    return h;
}

__device__ __forceinline__ float4 h4_fin(H4 h) {
    while ((u32)(h.v0 >> 32) != h.want || (u32)(h.v1 >> 32) != h.want ||
           (u32)(h.v2 >> 32) != h.want || (u32)(h.v3 >> 32) != h.want) {
        __builtin_amdgcn_s_sleep(4);    // rare: post-gate miss only
        h.v0 = HLD(h.p + 0); h.v1 = HLD(h.p + 1); h.v2 = HLD(h.p + 2); h.v3 = HLD(h.p + 3);
    }
    return make_float4(__uint_as_float((u32)h.v0), __uint_as_float((u32)h.v1),
                       __uint_as_float((u32)h.v2), __uint_as_float((u32)h.v3));
}

// ---- block-level gate on hist tags: ONE thread polls two sample words ----
__device__ __forceinline__ void gate_wait(const u64* __restrict__ w0, const u64* __restrict__ w1,
                                          u32 want0, u32 want1) {
    if (threadIdx.x == 0) {
        for (;;) {
            u32 g0 = (u32)(HLD(w0) >> 32);
            u32 g1 = (u32)(HLD(w1) >> 32);
            if (g0 == want0 && g1 == want1) break;
            __builtin_amdgcn_s_sleep(16);
        }
    }
    __syncthreads();
}

// ---- block-level gate on a completion counter (acquire on exit for cache inv) ----
__device__ __forceinline__ void gate_cnt(const u32* __restrict__ c, u32 target) {
    if (threadIdx.x == 0) {
        while (__hip_atomic_load(c, __ATOMIC_RELAXED, __HIP_MEMORY_SCOPE_AGENT) < target)
            __builtin_amdgcn_s_sleep(16);
        (void)__hip_atomic_load(c, __ATOMIC_ACQUIRE, __HIP_MEMORY_SCOPE_AGENT);
    }
    __syncthreads();
}

// ---- GEMM micro-kernel pieces (64x64 tile, 16-deep K step, double-buffered LDS) ----
__device__ __forceinline__ void stage_nb(float (*As)[68], float (*Bs)[68],
                                         int lk, int lr, float4 av, float4 bv) {
    As[lk + 0][lr] = av.x; As[lk + 1][lr] = av.y; As[lk + 2][lr] = av.z; As[lk + 3][lr] = av.w;
    Bs[lk + 0][lr] = bv.x; Bs[lk + 1][lr] = bv.y; Bs[lk + 2][lr] = bv.z; Bs[lk + 3][lr] = bv.w;
}

__device__ __forceinline__ void fma16(float acc[4][4], const float (*As)[68], const float (*Bs)[68],
                                      int tx, int ty) {
    #pragma unroll
    for (int kk = 0; kk < 16; ++kk) {
        float4 a4 = *(const float4*)&As[kk][ty * 4];
        float4 b4 = *(const float4*)&Bs[kk][tx * 4];
        acc[0][0] += a4.x * b4.x; acc[0][1] += a4.x * b4.y; acc[0][2] += a4.x * b4.z; acc[0][3] += a4.x * b4.w;
        acc[1][0] += a4.y * b4.x; acc[1][1] += a4.y * b4.y; acc[1][2] += a4.y * b4.z; acc[1][3] += a4.y * b4.w;
        acc[2][0] += a4.z * b4.x; acc[2][1] += a4.z * b4.y; acc[2][2] += a4.z * b4.z; acc[2][3] += a4.z * b4.w;
        acc[3][0] += a4.w * b4.x; acc[3][1] += a4.w * b4.y; acc[3][2] += a4.w * b4.z; acc[3][3] += a4.w * b4.w;
    }
}

// one K-segment of a hist-consuming GEMM, software-pipelined one step deep.
__device__ __forceinline__ void gemm_seg(float (*AsB)[16][68], float (*BsB)[16][68],
        float acc[4][4], const u64* __restrict__ hist, int t, int tind, u32 base,
        const float* __restrict__ brow, int kb, int klen,
        int lk, int lr, int tx, int ty, int& pb)
{
    int ka = kb + lk;
    H4 h = h4_issue(hist, ka < 800 ? t : tind, ka < 800 ? ka : ka - 800, base);
    float4 bv = *(const float4*)(brow + ka);
    for (int k0 = kb; k0 < kb + klen; k0 += 16) {
        float4 av = h4_fin(h);
        stage_nb(AsB[pb], BsB[pb], lk, lr, av, bv);
        int kn = k0 + 16;
        if (kn < kb + klen) {
            int k2 = kn + lk;
            h  = h4_issue(hist, k2 < 800 ? t : tind, k2 < 800 ? k2 : k2 - 800, base);
            bv = *(const float4*)(brow + k2);
        }
        __syncthreads();                 // single barrier per K-step (double buffer)
        fma16(acc, AsB[pb], BsB[pb], tx, ty);
        pb ^= 1;
    }
}

// ---------------- persistent distributed LSTM body ----------------
// cntPre (L1): gate on all 4 xg1-tile counters before starting (hist overwrite safety).
// cntXg  (L0): gate xg reads once per 64 steps on embed-tile counters.
#define LSTM_G 50
__device__ __forceinline__ void lstm_body(int bid,
                 const float* __restrict__ Whh,   // (2,1600,400)
                 const float* __restrict__ h0,    // (4,400)
                 const float* __restrict__ c0,    // (4,400)
                 int hc_base,
                 const float* __restrict__ xg,    // (256,3200): [t][d*1600 + gaterow]
                 u64* __restrict__ hist,          // (2,256,400)
                 u32 tag_base,
                 float (*hbuf)[416],
                 const u32* __restrict__ cntPre,
                 const u32* __restrict__ cntXg) {
    const int T = 256;
    int d  = bid / LSTM_G;
    int wg = bid % LSTM_G;
    int a8 = wg * 8;
    int tid = threadIdx.x;
    int w = tid >> 6, lane = tid & 63;
    int c = lane & 7, r = lane >> 3;
    int gate = r >> 1, jj = r & 1;
    int gr = gate * 400 + a8 + 2 * w + jj;

    float4 wv[13];
    const float* wrow = Whh + (size_t)d * 640000 + (size_t)gr * 400;
    #pragma unroll
    for (int i = 0; i < 13; ++i) {
        int k = 4 * (c + 8 * i);
        wv[i] = (k + 3 < 400) ? *(const float4*)(wrow + k) : make_float4(0.f, 0.f, 0.f, 0.f);
    }
    if (tid < 16) { hbuf[0][400 + tid] = 0.f; hbuf[1][400 + tid] = 0.f; }

    float c_state = 0.f;
    if (lane == 0 || lane == 8)
        c_state = c0[(hc_base + d) * 400 + a8 + 2 * w + jj];

    if (cntPre) { gate_cnt(&cntPre[0], 50); gate_cnt(&cntPre[1], 50);
                  gate_cnt(&cntPre[2], 50); gate_cnt(&cntPre[3], 50); }

    u64* hst = hist + (size_t)d * 102400;
    bool need2 = (tid + 256 < 400);

    for (int t = 0; t < T; ++t) {
        if (cntXg && (t & 63) == 0) {           // embed tile gate (uniform branch)
            int tile = d ? 3 - (t >> 6) : (t >> 6);
            gate_cnt(&cntXg[tile], 50);
        }
        int xt = d ? (T - 1 - t) : t;
        float xgv = xg[(size_t)xt * 3200 + d * 1600 + gr];
        float* hb = hbuf[t & 1];

        if (t == 0) {
            hb[tid] = h0[(hc_base + d) * 400 + tid];
            if (need2) hb[tid + 256] = h0[(hc_base + d) * 400 + tid + 256];
        } else {
            const u64* src = hst + (size_t)(t - 1) * 400;
            u32 want = tag_base + (u32)t;
            bool d1 = false, d2 = !need2;
            while (!(d1 && d2)) {
                u64 v1 = 0, v2 = 0;
                if (!d1) v1 = HLD(&src[tid]);
                if (!d2) v2 = HLD(&src[tid + 256]);
                if (!d1 && (u32)(v1 >> 32) == want) { hb[tid] = __uint_as_float((u32)v1); d1 = true; }
                if (!d2 && (u32)(v2 >> 32) == want) { hb[tid + 256] = __uint_as_float((u32)v2); d2 = true; }
            }
        }
        __syncthreads();

        const float4* h4 = (const float4*)hb;
        float s = 0.f;
        #pragma unroll
        for (int i = 0; i < 13; ++i) {
            float4 hv = h4[c + 8 * i];
            s += wv[i].x * hv.x + wv[i].y * hv.y + wv[i].z * hv.z + wv[i].w * hv.w;
        }
        s += __shfl_down(s, 4);
        s += __shfl_down(s, 2);
        s += __shfl_down(s, 1);

        float v = 0.f;
        if (c == 0) {
            float tot = s + xgv;
            float arg = (gate == 2) ? 2.f * tot : -tot;
            arg = fminf(fmaxf(arg, -60.f), 60.f);
            float e = __expf(arg);
            v = (gate == 2) ? (e - 1.f) * __frcp_rn(e + 1.f)
                            : __frcp_rn(1.f + e);
        }
        float fv = __shfl(v, lane + 16);
        float gv = __shfl(v, lane + 32);
        float ov = __shfl(v, lane + 48);
        if (lane == 0 || lane == 8) {
            c_state = fv * c_state + v * gv;
            float ec = __expf(fminf(fmaxf(2.f * c_state, -60.f), 60.f));
            float th = (ec - 1.f) * __frcp_rn(ec + 1.f);
            float h = ov * th;
            u64 pk = (((u64)(tag_base + t + 1)) << 32) | (u64)__float_as_uint(h);
            __hip_atomic_store(&hst[(size_t)t * 400 + a8 + 2 * w + jj], pk,
                               __ATOMIC_RELAXED, __HIP_MEMORY_SCOPE_AGENT);
        }
    }
}

// shared-memory union: GEMM tiles and LSTM hbuf never coexist in one block
union SmemU {
    struct { float As[2][16][68]; float Bs[2][16][68]; } g;
    float hbuf[2][416];
};

// ---------------- MEGA dispatch: embed + both LSTM layers + all hist GEMMs ----------------
// blocks   0..199: embed GEMM -> xg0 (t-tile order {0,3,1,2}; increments cnt[4+ttile])
// blocks 200..299: LSTM layer 0 (xg0 reads gated per 64 steps on cnt[4..7]; tags 1..256)
// blocks 300..499: xg1 GEMM (gated on layer-0 hist tags; increments cnt[t-tile])
// blocks 500..599: LSTM layer 1 (gated on cnt[0..3]==50; tags 257..512)
// blocks 600..799: PQ tiles   (row-gated on layer-1 hist tags; writes over xg0)
// blocks 800..999: ULVR tiles (row-gated; writes over xg1 -- safe, see layout note)
// 1000 blocks x 4 waves all co-resident -> no dispatch-order deadlock.
__global__ __launch_bounds__(256)
void mega_kernel(const int* __restrict__ words, const int* __restrict__ tags,
                 const float* __restrict__ wemb, const float* __restrict__ temb,
                 const float* __restrict__ Wih0, const float* __restrict__ bih0,
                 const float* __restrict__ bhh0,
                 const float* __restrict__ Whh0, const float* __restrict__ Whh1,
                 const float* __restrict__ h0, const float* __restrict__ c0,
                 float* __restrict__ xg0, float* __restrict__ xg1,
                 u64* __restrict__ hist, const int* __restrict__ arcs,
                 const float* __restrict__ Wih1, const float* __restrict__ bih1,
                 const float* __restrict__ bhh1,
                 const float* __restrict__ Wa1, const float* __restrict__ ba1,
                 const float* __restrict__ Wl1,
                 float* __restrict__ PQ, float* __restrict__ ULVR,
                 u32* __restrict__ cnt) {
    __shared__ SmemU sm;
    int bid = blockIdx.x;
    int tid = threadIdx.x;
    int tx = tid & 15, ty = tid >> 4;
    int lr = tid >> 2, lk = (tid & 3) * 4;

    if (bid < 200) {            // ---- embed GEMM: xg0[t][n] = [wemb|temb] @ Wih0 + biases ----
        int ttile, nt;
        if (bid < 100) { ttile = (bid & 1) * 3;  nt = bid >> 1; }          // tiles 0,3 first
        else           { ttile = 1 + (bid & 1);  nt = (bid - 100) >> 1; }  // then 1,2
        int t0 = ttile * 64, n0 = nt * 64;
        float acc[4][4] = {};
        int t = t0 + lr;
        const float* arow0 = wemb + (size_t)words[t] * 300;
        const float* arow1 = temb + (size_t)tags[t] * 100 - 300;   // indexed by k directly
        const float* brow  = Wih0 + (size_t)(n0 + lr) * 400;

        int p = 0;
        float4 av, bv;
        { int k = lk; av = (k < 300) ? *(const float4*)(arow0 + k) : *(const float4*)(arow1 + k);
          bv = *(const float4*)(brow + k); }
        for (int k0 = 0; k0 < 400; k0 += 16) {
            stage_nb(sm.g.As[p], sm.g.Bs[p], lk, lr, av, bv);
            int kn = k0 + 16;
            if (kn < 400) {
                int k = kn + lk;   // 300 % 4 == 0, so each float4 stays in one table
                av = (k < 300) ? *(const float4*)(arow0 + k) : *(const float4*)(arow1 + k);
                bv = *(const float4*)(brow + k);
            }
            __syncthreads();
            fma16(acc, sm.g.As[p], sm.g.Bs[p], tx, ty);
            p ^= 1;
        }
        float bs[4];
        #pragma unroll
        for (int j = 0; j < 4; ++j) {
            int n = n0 + tx * 4 + j;
            bs[j] = bih0[n] + bhh0[n];
        }
        #pragma unroll
        for (int i = 0; i < 4; ++i) {
            int tr = t0 + ty * 4 + i;
            float4 o;
            o.x = acc[i][0] + bs[0]; o.y = acc[i][1] + bs[1];
            o.z = acc[i][2] + bs[2]; o.w = acc[i][3] + bs[3];
            *(float4*)(xg0 + (size_t)tr * 3200 + n0 + tx * 4) = o;
        }
        __syncthreads();        // all tile stores drained (vmcnt at barrier)
        if (tid == 0)
            __hip_atomic_fetch_add(&cnt[4 + ttile], 1u, __ATOMIC_RELEASE, __HIP_MEMORY_SCOPE_AGENT);
        return;
    }
    if (bid < 300) {            // ---- LSTM layer 0 ----
        lstm_body(bid - 200, Whh0, h0, c0, 0, xg0, hist, 0u, sm.hbuf, nullptr, cnt + 4);
        return;
    }
    if (bid < 500) {            // ---- xg1 GEMM ----
        int g = bid - 300;
        int t0 = (g & 3) * 64;
        int n0 = (g >> 2) * 64;
        float acc[4][4] = {};
        int t = t0 + lr;
        const float* brow = Wih1 + (size_t)(n0 + lr) * 800;

        int first = (t0 >= 128) ? 400 : 0;
        int pb = 0;
        for (int seg = 0; seg < 2; ++seg) {
            int kb = first ^ (seg ? 400 : 0);
            if (kb == 0) {      // fwd rows t0..t0+63: last produced at fwd step t0+63
                const u64* gw = hist + (size_t)(t0 + 63) * 400;
                gate_wait(gw, gw + 399, (u32)(t0 + 64), (u32)(t0 + 64));
            } else {            // bwd slots 255-t, max slot = 255-t0 (for row t0)
                const u64* gw = hist + 102400 + (size_t)(255 - t0) * 400;
                gate_wait(gw, gw + 399, (u32)(256 - t0), (u32)(256 - t0));
            }
            gemm_seg(sm.g.As, sm.g.Bs, acc, hist, t, t, 0u, brow, kb, 400, lk, lr, tx, ty, pb);
        }
        float bs[4];
        #pragma unroll
        for (int j = 0; j < 4; ++j) {
            int n = n0 + tx * 4 + j;
            bs[j] = bih1[n] + bhh1[n];
        }
        #pragma unroll
        for (int i = 0; i < 4; ++i) {
            int tr = t0 + ty * 4 + i;
            float4 o;
            o.x = acc[i][0] + bs[0]; o.y = acc[i][1] + bs[1];
            o.z = acc[i][2] + bs[2]; o.w = acc[i][3] + bs[3];
            *(float4*)(xg1 + (size_t)tr * 3200 + n0 + tx * 4) = o;
        }
        __syncthreads();        // all tile writes drained
        if (tid == 0)
            __hip_atomic_fetch_add(&cnt[t0 >> 6], 1u, __ATOMIC_RELEASE, __HIP_MEMORY_SCOPE_AGENT);
        return;
    }
    if (bid < 600) {            // ---- LSTM layer 1 ----
        lstm_body(bid - 500, Whh1, h0, c0, 2, xg1, hist, 256u, sm.hbuf, cnt, nullptr);
        return;
    }

    // ---- PQ / ULVR tiles: ensure all xg1 GEMMs done (hist fully holds this-launch
    // layer-0 tags -> layer-1 tag matches below cannot be stale from a previous replay).
    gate_cnt(&cnt[0], 50); gate_cnt(&cnt[1], 50); gate_cnt(&cnt[2], 50); gate_cnt(&cnt[3], 50);

    float acc[4][4] = {};
    int pb = 0;
    int g  = (bid < 800) ? bid - 600 : bid - 800;
    int t0 = (g & 3) * 64;
    int n0 = (g >> 2) * 64;
    int t = t0 + lr;
    int first = (t0 >= 128) ? 400 : 0;
    int nn = n0 + lr;
    const float* W  = (bid < 800) ? Wa1 : Wl1;
    const float* brow = (nn < 1600) ? W + (size_t)nn * 1600
                                    : W + (size_t)(nn - 1600) * 1600 + 800;
    for (int seg = 0; seg < 2; ++seg) {
        int kb = first ^ (seg ? 400 : 0);
        if (kb == 0) {
            const u64* gw = hist + (size_t)(t0 + 63) * 400;
            gate_wait(gw, gw + 399, (u32)(t0 + 320), (u32)(t0 + 320));
        } else {
            const u64* gw = hist + 102400 + (size_t)(255 - t0) * 400;
            gate_wait(gw, gw + 399, (u32)(512 - t0), (u32)(512 - t0));
        }
        gemm_seg(sm.g.As, sm.g.Bs, acc, hist, t, t, 256u, brow, kb, 400, lk, lr, tx, ty, pb);
    }
    float bs[4];
    float* dst;
    if (bid < 800) {            // PQ: P cols get ba1, Q cols 0
        #pragma unroll
        for (int j = 0; j < 4; ++j) {
            int n = n0 + tx * 4 + j;
            bs[j] = (n < 1600) ? ba1[n] : 0.f;
        }
        dst = PQ;
    } else {                    // ULVR: bias folded into label fusion
        #pragma unroll
        for (int j = 0; j < 4; ++j) bs[j] = 0.f;
        dst = ULVR;
    }
    #pragma unroll
    for (int i = 0; i < 4; ++i) {
        int tr = t0 + ty * 4 + i;
        float4 o;
        o.x = acc[i][0] + bs[0]; o.y = acc[i][1] + bs[1];
        o.z = acc[i][2] + bs[2]; o.w = acc[i][3] + bs[3];
        *(float4*)(dst + (size_t)tr * 3200 + n0 + tx * 4) = o;
    }
}

// ---------------- arc pairwise scorer: 8x8 tiles, 1024 blocks ----------------
__global__ __launch_bounds__(256)
void arc_kernel(const float* __restrict__ PQ,
                const float* __restrict__ Wa2, const float* __restrict__ ba2,
                float* __restrict__ out) {
    int i0 = blockIdx.x * 8, j0 = blockIdx.y * 8;
    int tid = threadIdx.x;
    __shared__ float Pt[8][66], Qt[8][66];
    __shared__ float W2f[1600];
    __shared__ float part[4][64];

    if (blockIdx.x == 0 && blockIdx.y == 0) {   // borders: row 0 (with [0,0]=1) and col 0
        if (tid < 257) out[tid] = (tid == 0) ? 1.0f : 0.0f;
        out[(size_t)(tid + 1) * 257] = 0.0f;
        if (tid == 0) out[0] = 1.0f;
    }
    for (int m = tid; m < 1600; m += 256) W2f[m] = Wa2[m];

    int out_i = tid & 63, ii = out_i >> 3, jj = out_i & 7, mc = tid >> 6;
    int slr = tid >> 5, slc = (tid & 31) * 2;   // stage: 8 rows x 64 cols via float2
    float acc = 0.f;
    for (int m0 = 0; m0 < 1600; m0 += 64) {
        float2 pv = *(const float2*)(PQ + (size_t)(i0 + slr) * 3200 + m0 + slc);
        float2 qv = *(const float2*)(PQ + (size_t)(j0 + slr) * 3200 + 1600 + m0 + slc);
        __syncthreads();
        Pt[slr][slc] = pv.x; Pt[slr][slc + 1] = pv.y;
        Qt[slr][slc] = qv.x; Qt[slr][slc + 1] = qv.y;
        __syncthreads();
        #pragma unroll
        for (int mm = 0; mm < 16; ++mm) {
            int m = mc * 16 + mm;
            float s = Pt[ii][m] + Qt[jj][m];
            acc += W2f[m0 + m] * fast_tanh(s);
        }
    }
    part[mc][out_i] = acc;
    __syncthreads();
    if (tid < 64) {
        float raw = part[0][tid] + part[1][tid] + part[2][tid] + part[3][tid] + ba2[0];
        int gi = i0 + (tid >> 3), gj = j0 + (tid & 7);
        if (gi == gj) raw = 0.f;
        out[(size_t)(gi + 1) * 257 + (gj + 1)] = raw;
    }
}

// ---------------- label output (fused head-gather + tanh + GEMV) ----------------
// u = tanh(UL[t] + VR[head(t)] + bl1);  lab = u @ Wl2.T + bl2; zero if head==0.
__global__ __launch_bounds__(256)
void label_out_kernel(const float* __restrict__ ULVR, const float* __restrict__ Wl2,
                      const float* __restrict__ bl2, const float* __restrict__ bl1,
                      const int* __restrict__ arcs, float* __restrict__ out) {
    int t = blockIdx.x;
    __shared__ float u_l[1600];
    __shared__ float part[4][64];
    int tid = threadIdx.x;
    int h = arcs[1 + t];
    int tind = min(max(h - 1, 0), 255);
    const float* ua = ULVR + (size_t)t * 3200;
    const float* ur = ULVR + (size_t)tind * 3200 + 1600;
    for (int m = tid; m < 1600; m += 256)
        u_l[m] = fast_tanh(ua[m] + ur[m] + bl1[m]);
    __syncthreads();
    int n = tid & 63, p = tid >> 6;
    float acc = 0.f;
    if (n < 40) {
        const float4* wr4 = (const float4*)(Wl2 + (size_t)n * 1600 + p * 400);
        const float*  ub  = u_l + p * 400;
        for (int m = 0; m < 100; ++m) {
            float4 w = wr4[m];
            acc += ub[4*m] * w.x + ub[4*m+1] * w.y + ub[4*m+2] * w.z + ub[4*m+3] * w.w;
        }
    }
    part[p][n] = acc;
    __syncthreads();
    if (tid < 40) {
        float v = part[0][tid] + part[1][tid] + part[2][tid] + part[3][tid] + bl2[tid];
        if (arcs[1 + t] == 0) v = 0.f;
        out[(size_t)t * 40 + tid] = v;
    }
}

// ---------------- launch ----------------
extern "C" void kernel_launch(void* const* d_in, const int* in_sizes, int n_in,
                              void* d_out, int out_size, void* d_ws, size_t ws_size,
                              hipStream_t stream) {
    const int*   words = (const int*)d_in[0];
    const int*   tags  = (const int*)d_in[1];
    const int*   arcs  = (const int*)d_in[2];
    const float* h0    = (const float*)d_in[3];
    const float* c0    = (const float*)d_in[4];
    const float* wemb  = (const float*)d_in[5];
    const float* temb  = (const float*)d_in[6];
    const float* Wih0  = (const float*)d_in[7];
    const float* Whh0  = (const float*)d_in[8];
    const float* bih0  = (const float*)d_in[9];
    const float* bhh0  = (const float*)d_in[10];
    const float* Wih1  = (const float*)d_in[11];
    const float* Whh1  = (const float*)d_in[12];
    const float* bih1  = (const float*)d_in[13];
    const float* bhh1  = (const float*)d_in[14];
    const float* Wa1   = (const float*)d_in[15];
    const float* ba1   = (const float*)d_in[16];
    const float* Wa2   = (const float*)d_in[17];
    const float* ba2   = (const float*)d_in[18];
    const float* Wl1   = (const float*)d_in[19];
    const float* bl1   = (const float*)d_in[20];
    const float* Wl2   = (const float*)d_in[21];
    const float* bl2   = (const float*)d_in[22];
    float* out = (float*)d_out;

    char* ws = (char*)d_ws;
    float* xg0  = (float*)(ws + OF_XG);   // layer-0 gates; later overwritten by PQ
    u64*   hist = (u64*)  (ws + OF_H);
    float* xg1  = (float*)(ws + OF_PQ);   // layer-1 gates; later overwritten by ULVR
    float* PQ   = (float*)(ws + OF_XG);
    float* ULVR = (float*)(ws + OF_PQ);
    // 8 completion counters (4 xg1-tiles + 4 embed-tiles) live in score-matrix cells
    // that arc_kernel overwrites AFTER the mega dispatch -> replay-safe, no ws growth.
    u32*   cnt  = (u32*)out + 66040;

    hipMemsetAsync(cnt, 0, 32, stream);
    mega_kernel<<<1000, 256, 0, stream>>>(words, tags, wemb, temb, Wih0, bih0, bhh0,
                                          Whh0, Whh1, h0, c0, xg0, xg1, hist, arcs,
                                          Wih1, bih1, bhh1, Wa1, ba1, Wl1, PQ, ULVR, cnt);
    arc_kernel<<<dim3(32, 32), 256, 0, stream>>>(PQ, Wa2, ba2, out);
    label_out_kernel<<<256, 256, 0, stream>>>(ULVR, Wl2, bl2, bl1, arcs, out + 66049);
}